// Round 6
// baseline (986.754 us; speedup 1.0000x reference)
//
#include <hip/hip_runtime.h>
#include <stdint.h>

typedef unsigned short u16;
typedef unsigned int u32;
typedef __attribute__((ext_vector_type(8))) short short8;
typedef __attribute__((ext_vector_type(4))) float f32x4;

#define BB 4
#define TT 1024
#define CC 2048

// ---------- helpers ----------
__device__ __forceinline__ u16 f2bf(float f){
  union { float f; u32 u; } v; v.f = f;
  return (u16)((v.u + 0x7FFFu + ((v.u >> 16) & 1u)) >> 16);
}
__device__ __forceinline__ float bf2f(u16 h){
  union { u32 u; float f; } v; v.u = ((u32)h) << 16; return v.f;
}

__device__ __forceinline__ void gload16(const void* g, void* s){
  __builtin_amdgcn_global_load_lds((const __attribute__((address_space(1))) u32*)g,
                                   (__attribute__((address_space(3))) u32*)s, 16, 0, 0);
}

__device__ __forceinline__ float wave_sum64(float x){
  #pragma unroll
  for (int m = 1; m < 64; m <<= 1) x += __shfl_xor(x, m, 64);
  return x;
}

// DPP row (16-lane) rotate-add reduction — VALU-only, no LDS pipe
template<int N>
__device__ __forceinline__ float ror_add(float x){
  int t = __builtin_amdgcn_update_dpp(0, __builtin_bit_cast(int, x), 0x120 | N, 0xF, 0xF, false);
  return x + __builtin_bit_cast(float, t);
}
__device__ __forceinline__ float red16(float x){
  x = ror_add<8>(x); x = ror_add<4>(x); x = ror_add<2>(x); x = ror_add<1>(x);
  return x;
}

// ---------- cast f32 -> bf16 ----------
__global__ __launch_bounds__(256) void k_cast(const float* __restrict__ in, u16* __restrict__ out, int n){
  int i = (blockIdx.x*256 + threadIdx.x)*4;
  if (i >= n) return;
  float4 v = *(const float4*)&in[i];
  *(ushort4*)&out[i] = make_ushort4(f2bf(v.x), f2bf(v.y), f2bf(v.z), f2bf(v.w));
}

// ---------- transpose + pad ----------
__global__ __launch_bounds__(256) void k_tpad(const float* __restrict__ in, u16* __restrict__ out,
                                              int R, int S, int Rpad, int Spad){
  int idx = blockIdx.x*256 + threadIdx.x;
  if (idx >= Rpad*Spad) return;
  int s = idx / Rpad, r = idx - s*Rpad;
  float v = (s < S && r < R) ? in[(size_t)r*S + s] : 0.f;
  out[idx] = f2bf(v);
}

// ---------- GEMM: C[M,N] = A[M,K](bf16) * Bt[N,K]^T(bf16) ----------
// AMODE 0: A from bf16 buffer. AMODE 1: on-the-fly mix, select by bx (stage-1).
// AMODE 2: on-the-fly mix, select by bx>>4 (fused r/k/v; C base offset (bx>>4)*M*ldc).
// EPI 0: f32 out. EPI 1: bf16 out. EPI 2: bf16 out + stage-1 activation by bx.
template<int AMODE, int EPI>
__global__ __launch_bounds__(256) void k_gemm(
  const u16* __restrict__ Abf,
  const float* __restrict__ xg, const float* __restrict__ shiftg,
  const float* __restrict__ mx0, const float* __restrict__ mx1,
  const float* __restrict__ mx2, const float* __restrict__ mx3,
  const u16* __restrict__ Bt, float* __restrict__ Cf, u16* __restrict__ Cb,
  int K, int lda, int ldb, int ldc)
{
  __shared__ alignas(16) u16 sA[128*32];
  __shared__ alignas(16) u16 sB[128*32];
  const int tid = threadIdx.x;
  const int wv = tid >> 6, ln = tid & 63;
  const int bx = blockIdx.x;
  const int row0 = blockIdx.y * 128, col0 = bx * 128;
  const int wr = wv >> 1, wc = wv & 1;
  const float* mixv = nullptr;
  if (AMODE == 1) mixv = (bx==0) ? mx0 : (bx==1) ? mx1 : (bx==2) ? mx2 : mx3;
  if (AMODE == 2){ int sel = bx >> 4; mixv = (sel==0) ? mx0 : (sel==1) ? mx1 : mx2; }

  f32x4 acc[4][4] = {};
  const int ob0 = wv*2048;
  const int o0  = ob0 + ln*16;
  const int rA0 = o0 >> 6;
  const int ke0 = (o0 & 63) >> 1;
  const int ar  = tid >> 2;
  const int akc = (tid & 3) * 8;

  for (int k0 = 0; k0 < K; k0 += 32){
    __syncthreads();
    if (AMODE == 0){
      gload16(&Abf[(size_t)(row0 + rA0     )*lda + k0 + ke0], (void*)((char*)sA + ob0));
      gload16(&Abf[(size_t)(row0 + rA0 + 16)*lda + k0 + ke0], (void*)((char*)sA + ob0 + 1024));
    }
    gload16(&Bt[(size_t)(col0 + rA0     )*ldb + k0 + ke0], (void*)((char*)sB + ob0));
    gload16(&Bt[(size_t)(col0 + rA0 + 16)*ldb + k0 + ke0], (void*)((char*)sB + ob0 + 1024));
    if (AMODE >= 1){
      float4 m0 = *(const float4*)&mixv[k0 + akc];
      float4 m1 = *(const float4*)&mixv[k0 + akc + 4];
      #pragma unroll
      for (int it = 0; it < 2; ++it){
        int r = ar + it*64;
        int gr = row0 + r;
        size_t xo = (size_t)gr*CC + k0 + akc;
        float4 c0 = *(const float4*)&xg[xo];
        float4 c1 = *(const float4*)&xg[xo + 4];
        const float* pp = ((gr & (TT-1)) == 0) ? &shiftg[(size_t)(gr >> 10)*CC + k0 + akc]
                                               : &xg[xo - CC];
        float4 p0 = *(const float4*)&pp[0];
        float4 p1 = *(const float4*)&pp[4];
        short8 vv;
        vv[0] = (short)f2bf(c0.x + (p0.x - c0.x)*m0.x);
        vv[1] = (short)f2bf(c0.y + (p0.y - c0.y)*m0.y);
        vv[2] = (short)f2bf(c0.z + (p0.z - c0.z)*m0.z);
        vv[3] = (short)f2bf(c0.w + (p0.w - c0.w)*m0.w);
        vv[4] = (short)f2bf(c1.x + (p1.x - c1.x)*m1.x);
        vv[5] = (short)f2bf(c1.y + (p1.y - c1.y)*m1.y);
        vv[6] = (short)f2bf(c1.z + (p1.z - c1.z)*m1.z);
        vv[7] = (short)f2bf(c1.w + (p1.w - c1.w)*m1.w);
        *(short8*)&sA[r*32 + akc] = vv;
      }
    }
    __syncthreads();
    short8 aF[4], bF[4];
    #pragma unroll
    for (int m=0;m<4;m++) aF[m] = *(const short8*)&sA[(wr*64 + m*16 + (ln&15))*32 + (ln>>4)*8];
    #pragma unroll
    for (int n=0;n<4;n++) bF[n] = *(const short8*)&sB[(wc*64 + n*16 + (ln&15))*32 + (ln>>4)*8];
    #pragma unroll
    for (int m=0;m<4;m++)
      #pragma unroll
      for (int n=0;n<4;n++)
        acc[m][n] = __builtin_amdgcn_mfma_f32_16x16x32_bf16(aF[m], bF[n], acc[m][n], 0,0,0);
  }

  const int cr = (ln >> 4) * 4, ccol = ln & 15;
  u16* Cbb = Cb;
  int cshift = 0;
  if (AMODE == 2){ Cbb = Cb + (size_t)(bx >> 4) * (4096u * 2048u); cshift = (bx >> 4) * 2048; }
  #pragma unroll
  for (int m=0;m<4;m++){
    #pragma unroll
    for (int n=0;n<4;n++){
      int gc = col0 + wc*64 + n*16 + ccol;
      #pragma unroll
      for (int j=0;j<4;j++){
        int gr = row0 + wr*64 + m*16 + cr + j;
        float v = acc[m][n][j];
        if (EPI == 0){
          Cf[(size_t)gr*ldc + gc] = v;
        } else if (EPI == 1){
          Cbb[(size_t)gr*ldc + (gc - cshift)] = f2bf(v);
        } else {
          if (bx == 0) v = tanhf(v);
          else if (bx >= 3) v = 1.f/(1.f + expf(-v));
          Cb[(size_t)gr*ldc + gc] = f2bf(v);
        }
      }
    }
  }
}

// ---------- post1: elementwise + kk-normalize (b staged NEGATED for scan) ----------
__global__ __launch_bounds__(256) void k_post1(
  u16* __restrict__ kb, u16* __restrict__ vb, const u16* __restrict__ winb,
  u16* __restrict__ ainb, u16* __restrict__ vinb,
  const float* __restrict__ vfirst,
  const float* __restrict__ w0, const float* __restrict__ a0, const float* __restrict__ v0,
  const float* __restrict__ kkv, const float* __restrict__ kav,
  float* __restrict__ dec)
{
  int grp = blockIdx.x*4 + (threadIdx.x >> 6);
  int n = threadIdx.x & 63;
  int i = grp >> 5, h = grp & 31;
  int c = h*64 + n;
  size_t idx = (size_t)i*CC + c;
  float k  = bf2f(kb[idx]),  v = bf2f(vb[idx]);
  float wi = bf2f(winb[idx]), ai = bf2f(ainb[idx]), vi = bf2f(vinb[idx]);
  float vf = vfirst[idx];
  float a  = 1.f/(1.f + expf(-(a0[c] + ai)));
  float z  = -(w0[c] + wi);
  float sp = (z > 15.f) ? z : log1pf(expf(z));
  float decay = expf(-expf(-sp - 0.5f));
  float vg = 1.f/(1.f + expf(-(v0[c] + vi)));
  float vfin = v + (vf - v)*vg;
  float kkr = k * kkv[c];
  float ss = wave_sum64(kkr*kkr);
  float kkn = kkr / fmaxf(sqrtf(ss), 1e-12f);
  float kfin = k * (1.f + (a - 1.f)*kav[c]);
  kb[idx] = f2bf(kfin);
  vb[idx] = f2bf(vfin);
  dec[idx] = decay;
  vinb[idx] = f2bf(kkn);
  ainb[idx] = f2bf(-(kkn * a));   // pre-negated b for the scan
}

// ---------- WKV scan v5: 2048 blocks = 16 row-segs x 128 (b,h); 64 threads (1 wave) ----------
// blk = seg*128 + bh  =>  XCD (blk%8) = bh%8: all 16 segs of a (b,h) share one XCD's L2.
// Lane (rql=ln>>4, cg=ln&15): owns S[seg*4+rql][cg*4 .. +3] in 4 registers.
// 8 waves/CU (2/SIMD) so dep-chain stalls cross-hide. 4 rotating 4-step chunks. No LDS.
#define DECL_CHUNK(S) float4 w##S[4]; ushort4 b##S[4], k##S[4], kk##S[4], r##S[4]; u16 v##S[4];

#define SCAN_ISSUE(S, t0) do {                                                   \
  _Pragma("unroll")                                                              \
  for (int s_=0; s_<4; ++s_){                                                    \
    size_t o_ = gc0 + (size_t)((t0)+s_)*CC;                                      \
    w##S[s_]  = *(const float4*)&wb[o_];                                         \
    b##S[s_]  = *(const ushort4*)&bbp[o_];                                       \
    k##S[s_]  = *(const ushort4*)&kb[o_];                                        \
    kk##S[s_] = *(const ushort4*)&kkb[o_];                                       \
    r##S[s_]  = *(const ushort4*)&rb[o_];                                        \
    v##S[s_]  = vb[gv0 + (size_t)((t0)+s_)*CC];                                  \
  }                                                                              \
} while(0)

#define SCAN_CHUNK(S, t0) do {                                                   \
  _Pragma("unroll")                                                              \
  for (int s_=0; s_<4; ++s_){                                                    \
    const float w_0=w##S[s_].x, w_1=w##S[s_].y, w_2=w##S[s_].z, w_3=w##S[s_].w;  \
    const float b_0=bf2f(b##S[s_].x), b_1=bf2f(b##S[s_].y),                      \
                b_2=bf2f(b##S[s_].z), b_3=bf2f(b##S[s_].w);                      \
    const float k_0=bf2f(k##S[s_].x), k_1=bf2f(k##S[s_].y),                      \
                k_2=bf2f(k##S[s_].z), k_3=bf2f(k##S[s_].w);                      \
    const float q_0=bf2f(kk##S[s_].x), q_1=bf2f(kk##S[s_].y),                    \
                q_2=bf2f(kk##S[s_].z), q_3=bf2f(kk##S[s_].w);                    \
    const float r_0=bf2f(r##S[s_].x), r_1=bf2f(r##S[s_].y),                      \
                r_2=bf2f(r##S[s_].z), r_3=bf2f(r##S[s_].w);                      \
    const float vv_ = bf2f(v##S[s_]);                                            \
    float p_ = fmaf(st[0],q_0, st[1]*q_1) + fmaf(st[2],q_2, st[3]*q_3);          \
    p_ = red16(p_);                                                              \
    st[0] = fmaf(st[0],w_0, fmaf(p_,b_0, vv_*k_0));                              \
    st[1] = fmaf(st[1],w_1, fmaf(p_,b_1, vv_*k_1));                              \
    st[2] = fmaf(st[2],w_2, fmaf(p_,b_2, vv_*k_2));                              \
    st[3] = fmaf(st[3],w_3, fmaf(p_,b_3, vv_*k_3));                              \
    float y_ = fmaf(st[0],r_0, st[1]*r_1) + fmaf(st[2],r_2, st[3]*r_3);          \
    y_ = red16(y_);                                                              \
    if (cg == 0) yb[gv0 + (size_t)((t0)+s_)*CC] = f2bf(y_);                      \
  }                                                                              \
} while(0)

__global__ __launch_bounds__(64) void k_scan(
  const u16* __restrict__ rb, const float* __restrict__ wb,
  const u16* __restrict__ kb, const u16* __restrict__ vb,
  const u16* __restrict__ kkb, const u16* __restrict__ bbp,
  const float* __restrict__ wkv_in, u16* __restrict__ yb, float* __restrict__ wkv_out)
{
  const int blk = blockIdx.x;
  const int bh = blk & 127, seg = blk >> 7;   // XCD = blk%8 = bh%8: segs of bh share L2
  const int b = bh >> 5, h = bh & 31;
  const int ln = threadIdx.x;
  const int rql = ln >> 4;           // row-in-seg 0..3
  const int cg = ln & 15;            // col group 0..15
  const int row = seg*4 + rql;
  const int col0 = cg*4;

  float st[4];
  {
    float4 a = *(const float4*)&wkv_in[((size_t)bh*64 + row)*64 + col0];
    st[0]=a.x; st[1]=a.y; st[2]=a.z; st[3]=a.w;
  }

  const size_t gc0 = ((size_t)b*TT)*CC + h*64 + col0;          // col-data base
  const size_t gv0 = ((size_t)b*TT)*CC + h*64 + row;           // v / y base

  DECL_CHUNK(A) DECL_CHUNK(B) DECL_CHUNK(C) DECL_CHUNK(D)

  SCAN_ISSUE(A, 0);
  SCAN_ISSUE(B, 4);
  SCAN_ISSUE(C, 8);
  for (int it = 0; it < 64; ++it){
    const int t0 = it*16;
    if (t0+12 < TT) SCAN_ISSUE(D, t0+12);
    SCAN_CHUNK(A, t0);
    if (t0+16 < TT) SCAN_ISSUE(A, t0+16);
    SCAN_CHUNK(B, t0+4);
    if (t0+20 < TT) SCAN_ISSUE(B, t0+20);
    SCAN_CHUNK(C, t0+8);
    if (t0+24 < TT) SCAN_ISSUE(C, t0+24);
    SCAN_CHUNK(D, t0+12);
  }

  *(float4*)&wkv_out[((size_t)bh*64 + row)*64 + col0] =
      make_float4(st[0], st[1], st[2], st[3]);
}

// ---------- post2 ----------
__global__ __launch_bounds__(256) void k_post2(
  const u16* __restrict__ ybuf, const u16* __restrict__ rbuf,
  const u16* __restrict__ kfb, const u16* __restrict__ vfb,
  const u16* __restrict__ gbuf, const float* __restrict__ rk,
  const float* __restrict__ lnw, const float* __restrict__ lnb, u16* __restrict__ ao)
{
  int grp = blockIdx.x*4 + (threadIdx.x >> 6);
  int n = threadIdx.x & 63;
  int i = grp >> 5, h = grp & 31;
  int c = h*64 + n;
  size_t idx = (size_t)i*CC + c;
  float y = bf2f(ybuf[idx]);
  float s1 = wave_sum64(y);
  float s2 = wave_sum64(y*y);
  float mu = s1 * (1.f/64.f);
  float var = s2 * (1.f/64.f) - mu*mu;
  float yn = (y - mu) * rsqrtf(var + 6.4e-4f) * lnw[c] + lnb[c];
  float rv = bf2f(rbuf[idx]), kv = bf2f(kfb[idx]);
  float s3 = wave_sum64(rv * kv * rk[c]);
  float bonus = s3 * bf2f(vfb[idx]);
  ao[idx] = f2bf((yn + bonus) * bf2f(gbuf[idx]));
}

// ---------- shift_state_out = x[:, -1] ----------
__global__ __launch_bounds__(256) void k_shift(const float* __restrict__ x, float* __restrict__ so){
  int i = blockIdx.x*256 + threadIdx.x;
  int b = i >> 9, c4 = (i & 511)*4;
  *(float4*)&so[(size_t)b*CC + c4] = *(const float4*)&x[((size_t)(b*TT + TT-1))*CC + c4];
}

// ---------- launch ----------
extern "C" void kernel_launch(void* const* d_in, const int* in_sizes, int n_in,
                              void* d_out, int out_size, void* d_ws, size_t ws_size,
                              hipStream_t stream)
{
  const float* x        = (const float*)d_in[0];
  const float* shift_in = (const float*)d_in[1];
  const float* wkv_in   = (const float*)d_in[2];
  const float* v_first  = (const float*)d_in[3];
  const float* x_r = (const float*)d_in[4];
  const float* x_w = (const float*)d_in[5];
  const float* x_k = (const float*)d_in[6];
  const float* x_v = (const float*)d_in[7];
  const float* x_a = (const float*)d_in[8];
  const float* x_g = (const float*)d_in[9];
  const float* w0 = (const float*)d_in[10];
  const float* w1 = (const float*)d_in[11];
  const float* w2 = (const float*)d_in[12];
  const float* a0 = (const float*)d_in[13];
  const float* a1 = (const float*)d_in[14];
  const float* a2 = (const float*)d_in[15];
  const float* v0 = (const float*)d_in[16];
  const float* v1 = (const float*)d_in[17];
  const float* v2 = (const float*)d_in[18];
  const float* g1 = (const float*)d_in[19];
  const float* g2 = (const float*)d_in[20];
  const float* k_k = (const float*)d_in[21];
  const float* k_a = (const float*)d_in[22];
  const float* r_k = (const float*)d_in[23];
  const float* Wr = (const float*)d_in[24];
  const float* Wk = (const float*)d_in[25];
  const float* Wv = (const float*)d_in[26];
  const float* Wo = (const float*)d_in[27];
  const float* ln_w = (const float*)d_in[28];
  const float* ln_b = (const float*)d_in[29];

  // ---- ws layout ----
  char* ws = (char*)d_ws;
  u16* WOB  = (u16*)(ws + 0);
  u16* WRB  = (u16*)(ws + 8388608);   // WRB/WKB/WVB contiguous => fused rkv B
  u16* WKB  = (u16*)(ws + 16777216);
  u16* WVB  = (u16*)(ws + 25165824);
  u16* WCAT = (u16*)(ws + 33554432);
  u16* B2W  = (u16*)(ws + 36175872);
  u16* B2A  = (u16*)(ws + 36700160);
  u16* B2V  = (u16*)(ws + 37224448);
  u16* B2G  = (u16*)(ws + 37748736);
  u16* PBUF = (u16*)(ws + 38797312);
  u16* RB   = (u16*)(ws + 44040192);  // RB/KB/VB contiguous => fused rkv C
  u16* KB   = (u16*)(ws + 60817408);
  u16* VB   = (u16*)(ws + 77594624);
  u16* YB   = (u16*)(ws + 94371840);
  float* DEC  = (float*)(ws + 8388608);     // overlays dead WRB..PBUF (post1 -> scan)
  u16* AO   = (u16*)(ws + 8388608);         // overlays dead DEC (post2 -> final GEMM)

  // ---- d_out scratch ----
  float* out       = (float*)d_out;
  float* shift_out = out + 8388608;
  float* wkv_out   = out + 8396800;
  float* vf_out    = out + 8921088;
  u16* WINb = (u16*)d_out;
  u16* AINb = (u16*)((char*)d_out + 16777216);
  u16* VINb = (u16*)((char*)d_out + 35684352);
  u16* GB   = (u16*)((char*)d_out + 52461568);

  // weight casts
  k_cast<<<4096, 256, 0, stream>>>(Wr, WRB, 4194304);
  k_cast<<<4096, 256, 0, stream>>>(Wk, WKB, 4194304);
  k_cast<<<4096, 256, 0, stream>>>(Wv, WVB, 4194304);
  k_cast<<<4096, 256, 0, stream>>>(Wo, WOB, 4194304);

  // stage-1 fused weight + stage-2 weights
  k_tpad<<<1024, 256, 0, stream>>>(w1, WCAT,            2048,  96, 2048, 128);
  k_tpad<<<1024, 256, 0, stream>>>(a1, WCAT + 128*2048, 2048,  96, 2048, 128);
  k_tpad<<<1024, 256, 0, stream>>>(v1, WCAT + 256*2048, 2048,  64, 2048, 128);
  k_tpad<<<2048, 256, 0, stream>>>(g1, WCAT + 384*2048, 2048, 256, 2048, 256);
  k_tpad<<<1024, 256, 0, stream>>>(w2, B2W,  96, 2048, 128, 2048);
  k_tpad<<<1024, 256, 0, stream>>>(a2, B2A,  96, 2048, 128, 2048);
  k_tpad<<<1024, 256, 0, stream>>>(v2, B2V,  64, 2048, 128, 2048);
  k_tpad<<<2048, 256, 0, stream>>>(g2, B2G, 256, 2048, 256, 2048);

  // fused r/k/v GEMM (single launch; mix + output selected by bx>>4)
  k_gemm<2,1><<<dim3(48,32), 256, 0, stream>>>(nullptr, x, shift_in, x_r, x_k, x_v, x_v,
                                               WRB, nullptr, RB, 2048, 0, 2048, 2048);

  // fused stage-1
  k_gemm<1,2><<<dim3(5,32), 256, 0, stream>>>(nullptr, x, shift_in, x_w, x_a, x_v, x_g,
                                              WCAT, nullptr, PBUF, 2048, 0, 2048, 640);

  // stage-2 GEMMs
  k_gemm<0,1><<<dim3(16,32), 256, 0, stream>>>(PBUF+0,   nullptr,nullptr,nullptr,nullptr,nullptr,nullptr,
                                               B2W, nullptr, WINb, 128, 640, 128, 2048);
  k_gemm<0,1><<<dim3(16,32), 256, 0, stream>>>(PBUF+128, nullptr,nullptr,nullptr,nullptr,nullptr,nullptr,
                                               B2A, nullptr, AINb, 128, 640, 128, 2048);
  k_gemm<0,1><<<dim3(16,32), 256, 0, stream>>>(PBUF+256, nullptr,nullptr,nullptr,nullptr,nullptr,nullptr,
                                               B2V, nullptr, VINb, 128, 640, 128, 2048);
  k_gemm<0,1><<<dim3(16,32), 256, 0, stream>>>(PBUF+384, nullptr,nullptr,nullptr,nullptr,nullptr,nullptr,
                                               B2G, nullptr, GB,   256, 640, 256, 2048);

  // elementwise post
  k_post1<<<32768, 256, 0, stream>>>(KB, VB, WINb, AINb, VINb, v_first,
                                     w0, a0, v0, k_k, k_a, DEC);

  // sequential WKV scan (register-resident, LDS-free, XCD-L2-shared, 8 waves/CU)
  k_scan<<<2048, 64, 0, stream>>>(RB, DEC, KB, VB, VINb, AINb, wkv_in, YB, wkv_out);

  // groupnorm + bonus + gate
  k_post2<<<32768, 256, 0, stream>>>(YB, RB, KB, VB, GB, r_k, ln_w, ln_b, AO);

  // final GEMM -> out
  k_gemm<0,0><<<dim3(16,32), 256, 0, stream>>>(AO, nullptr,nullptr,nullptr,nullptr,nullptr,nullptr,
                                               WOB, out, nullptr, 2048, 2048, 2048, 2048);

  // small outputs last
  k_shift<<<8, 256, 0, stream>>>(x, shift_out);
  hipMemcpyAsync(vf_out, v_first, 33554432, hipMemcpyDeviceToDevice, stream);
}

// Round 7
// 843.293 us; speedup vs baseline: 1.1701x; 1.1701x over previous
//
#include <hip/hip_runtime.h>
#include <hip/hip_bf16.h>
#include <stdint.h>

typedef unsigned short u16;
typedef unsigned int u32;
typedef __attribute__((ext_vector_type(8))) short short8;
typedef __attribute__((ext_vector_type(4))) float f32x4;

#define BB 4
#define TT 1024
#define CC 2048

// ---------- helpers ----------
// Compiler-friendly bf16 convert (emits v_cvt_pk_bf16_f32; RNE like the old manual path)
__device__ __forceinline__ u16 f2bf(float f){
  __hip_bfloat16 h = __float2bfloat16(f);
  return *reinterpret_cast<u16*>(&h);
}
__device__ __forceinline__ float bf2f(u16 h){
  union { u32 u; float f; } v; v.u = ((u32)h) << 16; return v.f;
}

__device__ __forceinline__ void gload16(const void* g, void* s){
  __builtin_amdgcn_global_load_lds((const __attribute__((address_space(1))) u32*)g,
                                   (__attribute__((address_space(3))) u32*)s, 16, 0, 0);
}

__device__ __forceinline__ float wave_sum64(float x){
  #pragma unroll
  for (int m = 1; m < 64; m <<= 1) x += __shfl_xor(x, m, 64);
  return x;
}

// DPP row (16-lane) rotate-add reduction — VALU-only, no LDS pipe
template<int N>
__device__ __forceinline__ float ror_add(float x){
  int t = __builtin_amdgcn_update_dpp(0, __builtin_bit_cast(int, x), 0x120 | N, 0xF, 0xF, false);
  return x + __builtin_bit_cast(float, t);
}
__device__ __forceinline__ float red16(float x){
  x = ror_add<8>(x); x = ror_add<4>(x); x = ror_add<2>(x); x = ror_add<1>(x);
  return x;
}

// ---------- cast f32 -> bf16 ----------
__global__ __launch_bounds__(256) void k_cast(const float* __restrict__ in, u16* __restrict__ out, int n){
  int i = (blockIdx.x*256 + threadIdx.x)*4;
  if (i >= n) return;
  float4 v = *(const float4*)&in[i];
  *(ushort4*)&out[i] = make_ushort4(f2bf(v.x), f2bf(v.y), f2bf(v.z), f2bf(v.w));
}

// ---------- transpose + pad ----------
__global__ __launch_bounds__(256) void k_tpad(const float* __restrict__ in, u16* __restrict__ out,
                                              int R, int S, int Rpad, int Spad){
  int idx = blockIdx.x*256 + threadIdx.x;
  if (idx >= Rpad*Spad) return;
  int s = idx / Rpad, r = idx - s*Rpad;
  float v = (s < S && r < R) ? in[(size_t)r*S + s] : 0.f;
  out[idx] = f2bf(v);
}

// ---------- GEMM: C[M,N] = A[M,K](bf16) * Bt[N,K]^T(bf16) ----------
// AMODE 0: A from bf16 buffer. AMODE 1: on-the-fly mix, select by bx (stage-1).
// AMODE 2: on-the-fly mix, select by bx>>4 (fused r/k/v; C base offset (bx>>4)*M*ldc).
// EPI 0: f32 out. EPI 1: bf16 out. EPI 2: bf16 out + stage-1 activation by bx.
template<int AMODE, int EPI>
__global__ __launch_bounds__(256) void k_gemm(
  const u16* __restrict__ Abf,
  const float* __restrict__ xg, const float* __restrict__ shiftg,
  const float* __restrict__ mx0, const float* __restrict__ mx1,
  const float* __restrict__ mx2, const float* __restrict__ mx3,
  const u16* __restrict__ Bt, float* __restrict__ Cf, u16* __restrict__ Cb,
  int K, int lda, int ldb, int ldc)
{
  __shared__ alignas(16) u16 sA[128*32];
  __shared__ alignas(16) u16 sB[128*32];
  const int tid = threadIdx.x;
  const int wv = tid >> 6, ln = tid & 63;
  const int bx = blockIdx.x;
  const int row0 = blockIdx.y * 128, col0 = bx * 128;
  const int wr = wv >> 1, wc = wv & 1;
  const float* mixv = nullptr;
  if (AMODE == 1) mixv = (bx==0) ? mx0 : (bx==1) ? mx1 : (bx==2) ? mx2 : mx3;
  if (AMODE == 2){ int sel = bx >> 4; mixv = (sel==0) ? mx0 : (sel==1) ? mx1 : mx2; }

  f32x4 acc[4][4] = {};
  const int ob0 = wv*2048;
  const int o0  = ob0 + ln*16;
  const int rA0 = o0 >> 6;
  const int ke0 = (o0 & 63) >> 1;
  const int ar  = tid >> 2;
  const int akc = (tid & 3) * 8;

  for (int k0 = 0; k0 < K; k0 += 32){
    __syncthreads();
    if (AMODE == 0){
      gload16(&Abf[(size_t)(row0 + rA0     )*lda + k0 + ke0], (void*)((char*)sA + ob0));
      gload16(&Abf[(size_t)(row0 + rA0 + 16)*lda + k0 + ke0], (void*)((char*)sA + ob0 + 1024));
    }
    gload16(&Bt[(size_t)(col0 + rA0     )*ldb + k0 + ke0], (void*)((char*)sB + ob0));
    gload16(&Bt[(size_t)(col0 + rA0 + 16)*ldb + k0 + ke0], (void*)((char*)sB + ob0 + 1024));
    if (AMODE >= 1){
      float4 m0 = *(const float4*)&mixv[k0 + akc];
      float4 m1 = *(const float4*)&mixv[k0 + akc + 4];
      #pragma unroll
      for (int it = 0; it < 2; ++it){
        int r = ar + it*64;
        int gr = row0 + r;
        size_t xo = (size_t)gr*CC + k0 + akc;
        float4 c0 = *(const float4*)&xg[xo];
        float4 c1 = *(const float4*)&xg[xo + 4];
        const float* pp = ((gr & (TT-1)) == 0) ? &shiftg[(size_t)(gr >> 10)*CC + k0 + akc]
                                               : &xg[xo - CC];
        float4 p0 = *(const float4*)&pp[0];
        float4 p1 = *(const float4*)&pp[4];
        short8 vv;
        vv[0] = (short)f2bf(c0.x + (p0.x - c0.x)*m0.x);
        vv[1] = (short)f2bf(c0.y + (p0.y - c0.y)*m0.y);
        vv[2] = (short)f2bf(c0.z + (p0.z - c0.z)*m0.z);
        vv[3] = (short)f2bf(c0.w + (p0.w - c0.w)*m0.w);
        vv[4] = (short)f2bf(c1.x + (p1.x - c1.x)*m1.x);
        vv[5] = (short)f2bf(c1.y + (p1.y - c1.y)*m1.y);
        vv[6] = (short)f2bf(c1.z + (p1.z - c1.z)*m1.z);
        vv[7] = (short)f2bf(c1.w + (p1.w - c1.w)*m1.w);
        *(short8*)&sA[r*32 + akc] = vv;
      }
    }
    __syncthreads();
    short8 aF[4], bF[4];
    #pragma unroll
    for (int m=0;m<4;m++) aF[m] = *(const short8*)&sA[(wr*64 + m*16 + (ln&15))*32 + (ln>>4)*8];
    #pragma unroll
    for (int n=0;n<4;n++) bF[n] = *(const short8*)&sB[(wc*64 + n*16 + (ln&15))*32 + (ln>>4)*8];
    #pragma unroll
    for (int m=0;m<4;m++)
      #pragma unroll
      for (int n=0;n<4;n++)
        acc[m][n] = __builtin_amdgcn_mfma_f32_16x16x32_bf16(aF[m], bF[n], acc[m][n], 0,0,0);
  }

  const int cr = (ln >> 4) * 4, ccol = ln & 15;
  u16* Cbb = Cb;
  int cshift = 0;
  if (AMODE == 2){ Cbb = Cb + (size_t)(bx >> 4) * (4096u * 2048u); cshift = (bx >> 4) * 2048; }
  #pragma unroll
  for (int m=0;m<4;m++){
    #pragma unroll
    for (int n=0;n<4;n++){
      int gc = col0 + wc*64 + n*16 + ccol;
      #pragma unroll
      for (int j=0;j<4;j++){
        int gr = row0 + wr*64 + m*16 + cr + j;
        float v = acc[m][n][j];
        if (EPI == 0){
          Cf[(size_t)gr*ldc + gc] = v;
        } else if (EPI == 1){
          Cbb[(size_t)gr*ldc + (gc - cshift)] = f2bf(v);
        } else {
          if (bx == 0) v = tanhf(v);
          else if (bx >= 3) v = 1.f/(1.f + expf(-v));
          Cb[(size_t)gr*ldc + gc] = f2bf(v);
        }
      }
    }
  }
}

// ---------- post1: elementwise + kk-normalize (b staged NEGATED for scan) ----------
__global__ __launch_bounds__(256) void k_post1(
  u16* __restrict__ kb, u16* __restrict__ vb, const u16* __restrict__ winb,
  u16* __restrict__ ainb, u16* __restrict__ vinb,
  const float* __restrict__ vfirst,
  const float* __restrict__ w0, const float* __restrict__ a0, const float* __restrict__ v0,
  const float* __restrict__ kkv, const float* __restrict__ kav,
  float* __restrict__ dec)
{
  int grp = blockIdx.x*4 + (threadIdx.x >> 6);
  int n = threadIdx.x & 63;
  int i = grp >> 5, h = grp & 31;
  int c = h*64 + n;
  size_t idx = (size_t)i*CC + c;
  float k  = bf2f(kb[idx]),  v = bf2f(vb[idx]);
  float wi = bf2f(winb[idx]), ai = bf2f(ainb[idx]), vi = bf2f(vinb[idx]);
  float vf = vfirst[idx];
  float a  = 1.f/(1.f + expf(-(a0[c] + ai)));
  float z  = -(w0[c] + wi);
  float sp = (z > 15.f) ? z : log1pf(expf(z));
  float decay = expf(-expf(-sp - 0.5f));
  float vg = 1.f/(1.f + expf(-(v0[c] + vi)));
  float vfin = v + (vf - v)*vg;
  float kkr = k * kkv[c];
  float ss = wave_sum64(kkr*kkr);
  float kkn = kkr / fmaxf(sqrtf(ss), 1e-12f);
  float kfin = k * (1.f + (a - 1.f)*kav[c]);
  kb[idx] = f2bf(kfin);
  vb[idx] = f2bf(vfin);
  dec[idx] = decay;
  vinb[idx] = f2bf(kkn);
  ainb[idx] = f2bf(-(kkn * a));   // pre-negated b for the scan
}

// ---------- WKV scan v4 (best measured): 1024 blocks = 8 row-octets x 128 (b,h) ----------
// blk = oct*128 + bh  =>  XCD (blk%8) = bh%8: all 8 octets of a (b,h) share one XCD's L2.
// Lane (rg=ln>>4, cg=ln&15): owns S[oct*8+rg*2 .. +1][cg*4 .. +3] in 8 registers.
// 4 rotating 4-step chunks: prefetch depth 3. No LDS.
#define DECL_CHUNK(S) float4 w##S[4]; ushort4 b##S[4], k##S[4], kk##S[4], r##S[4]; u32 v##S[4];

#define SCAN_ISSUE(S, t0) do {                                                   \
  _Pragma("unroll")                                                              \
  for (int s_=0; s_<4; ++s_){                                                    \
    size_t o_ = gc0 + (size_t)((t0)+s_)*CC;                                      \
    w##S[s_]  = *(const float4*)&wb[o_];                                         \
    b##S[s_]  = *(const ushort4*)&bbp[o_];                                       \
    k##S[s_]  = *(const ushort4*)&kb[o_];                                        \
    kk##S[s_] = *(const ushort4*)&kkb[o_];                                       \
    r##S[s_]  = *(const ushort4*)&rb[o_];                                        \
    v##S[s_]  = *(const u32*)&vb[gv0 + (size_t)((t0)+s_)*CC];                    \
  }                                                                              \
} while(0)

#define SCAN_CHUNK(S, t0) do {                                                   \
  _Pragma("unroll")                                                              \
  for (int s_=0; s_<4; ++s_){                                                    \
    const float w_0=w##S[s_].x, w_1=w##S[s_].y, w_2=w##S[s_].z, w_3=w##S[s_].w;  \
    const float b_0=bf2f(b##S[s_].x), b_1=bf2f(b##S[s_].y),                      \
                b_2=bf2f(b##S[s_].z), b_3=bf2f(b##S[s_].w);                      \
    const float k_0=bf2f(k##S[s_].x), k_1=bf2f(k##S[s_].y),                      \
                k_2=bf2f(k##S[s_].z), k_3=bf2f(k##S[s_].w);                      \
    const float q_0=bf2f(kk##S[s_].x), q_1=bf2f(kk##S[s_].y),                    \
                q_2=bf2f(kk##S[s_].z), q_3=bf2f(kk##S[s_].w);                    \
    const float r_0=bf2f(r##S[s_].x), r_1=bf2f(r##S[s_].y),                      \
                r_2=bf2f(r##S[s_].z), r_3=bf2f(r##S[s_].w);                      \
    const u32 vpk_ = v##S[s_];                                                   \
    const float vv0_ = bf2f((u16)(vpk_ & 0xFFFFu));                              \
    const float vv1_ = bf2f((u16)(vpk_ >> 16));                                  \
    float p0_ = fmaf(st[0][0],q_0, st[0][1]*q_1) + fmaf(st[0][2],q_2, st[0][3]*q_3); \
    float p1_ = fmaf(st[1][0],q_0, st[1][1]*q_1) + fmaf(st[1][2],q_2, st[1][3]*q_3); \
    p0_ = red16(p0_); p1_ = red16(p1_);                                          \
    st[0][0] = fmaf(st[0][0],w_0, fmaf(p0_,b_0, vv0_*k_0));                      \
    st[0][1] = fmaf(st[0][1],w_1, fmaf(p0_,b_1, vv0_*k_1));                      \
    st[0][2] = fmaf(st[0][2],w_2, fmaf(p0_,b_2, vv0_*k_2));                      \
    st[0][3] = fmaf(st[0][3],w_3, fmaf(p0_,b_3, vv0_*k_3));                      \
    st[1][0] = fmaf(st[1][0],w_0, fmaf(p1_,b_0, vv1_*k_0));                      \
    st[1][1] = fmaf(st[1][1],w_1, fmaf(p1_,b_1, vv1_*k_1));                      \
    st[1][2] = fmaf(st[1][2],w_2, fmaf(p1_,b_2, vv1_*k_2));                      \
    st[1][3] = fmaf(st[1][3],w_3, fmaf(p1_,b_3, vv1_*k_3));                      \
    float y0_ = fmaf(st[0][0],r_0, st[0][1]*r_1) + fmaf(st[0][2],r_2, st[0][3]*r_3); \
    float y1_ = fmaf(st[1][0],r_0, st[1][1]*r_1) + fmaf(st[1][2],r_2, st[1][3]*r_3); \
    y0_ = red16(y0_); y1_ = red16(y1_);                                          \
    if (cg == 0){                                                                \
      u32 pk_ = (u32)f2bf(y0_) | ((u32)f2bf(y1_) << 16);                         \
      *(u32*)&yb[gv0 + (size_t)((t0)+s_)*CC] = pk_;                              \
    }                                                                            \
  }                                                                              \
} while(0)

__global__ __launch_bounds__(64) void k_scan(
  const u16* __restrict__ rb, const float* __restrict__ wb,
  const u16* __restrict__ kb, const u16* __restrict__ vb,
  const u16* __restrict__ kkb, const u16* __restrict__ bbp,
  const float* __restrict__ wkv_in, u16* __restrict__ yb, float* __restrict__ wkv_out)
{
  const int blk = blockIdx.x;
  const int bh = blk & 127, oct = blk >> 7;   // XCD = blk%8 = bh%8: octets of bh share L2
  const int b = bh >> 5, h = bh & 31;
  const int ln = threadIdx.x;
  const int rg = ln >> 4;            // row pair group 0..3
  const int cg = ln & 15;            // col group 0..15
  const int row0 = oct*8 + rg*2;
  const int col0 = cg*4;

  float st[2][4];
  {
    const float* sp0 = &wkv_in[((size_t)bh*64 + row0    )*64 + col0];
    const float* sp1 = &wkv_in[((size_t)bh*64 + row0 + 1)*64 + col0];
    float4 a = *(const float4*)sp0, c = *(const float4*)sp1;
    st[0][0]=a.x; st[0][1]=a.y; st[0][2]=a.z; st[0][3]=a.w;
    st[1][0]=c.x; st[1][1]=c.y; st[1][2]=c.z; st[1][3]=c.w;
  }

  const size_t gc0 = ((size_t)b*TT)*CC + h*64 + col0;          // col-data base
  const size_t gv0 = ((size_t)b*TT)*CC + h*64 + row0;          // v / y base

  DECL_CHUNK(A) DECL_CHUNK(B) DECL_CHUNK(C) DECL_CHUNK(D)

  SCAN_ISSUE(A, 0);
  SCAN_ISSUE(B, 4);
  SCAN_ISSUE(C, 8);
  for (int it = 0; it < 64; ++it){
    const int t0 = it*16;
    if (t0+12 < TT) SCAN_ISSUE(D, t0+12);
    SCAN_CHUNK(A, t0);
    if (t0+16 < TT) SCAN_ISSUE(A, t0+16);
    SCAN_CHUNK(B, t0+4);
    if (t0+20 < TT) SCAN_ISSUE(B, t0+20);
    SCAN_CHUNK(C, t0+8);
    if (t0+24 < TT) SCAN_ISSUE(C, t0+24);
    SCAN_CHUNK(D, t0+12);
  }

  {
    float* wo0 = &wkv_out[((size_t)bh*64 + row0    )*64 + col0];
    float* wo1 = &wkv_out[((size_t)bh*64 + row0 + 1)*64 + col0];
    *(float4*)wo0 = make_float4(st[0][0], st[0][1], st[0][2], st[0][3]);
    *(float4*)wo1 = make_float4(st[1][0], st[1][1], st[1][2], st[1][3]);
  }
}

// ---------- post2 ----------
__global__ __launch_bounds__(256) void k_post2(
  const u16* __restrict__ ybuf, const u16* __restrict__ rbuf,
  const u16* __restrict__ kfb, const u16* __restrict__ vfb,
  const u16* __restrict__ gbuf, const float* __restrict__ rk,
  const float* __restrict__ lnw, const float* __restrict__ lnb, u16* __restrict__ ao)
{
  int grp = blockIdx.x*4 + (threadIdx.x >> 6);
  int n = threadIdx.x & 63;
  int i = grp >> 5, h = grp & 31;
  int c = h*64 + n;
  size_t idx = (size_t)i*CC + c;
  float y = bf2f(ybuf[idx]);
  float s1 = wave_sum64(y);
  float s2 = wave_sum64(y*y);
  float mu = s1 * (1.f/64.f);
  float var = s2 * (1.f/64.f) - mu*mu;
  float yn = (y - mu) * rsqrtf(var + 6.4e-4f) * lnw[c] + lnb[c];
  float rv = bf2f(rbuf[idx]), kv = bf2f(kfb[idx]);
  float s3 = wave_sum64(rv * kv * rk[c]);
  float bonus = s3 * bf2f(vfb[idx]);
  ao[idx] = f2bf((yn + bonus) * bf2f(gbuf[idx]));
}

// ---------- shift_state_out = x[:, -1] ----------
__global__ __launch_bounds__(256) void k_shift(const float* __restrict__ x, float* __restrict__ so){
  int i = blockIdx.x*256 + threadIdx.x;
  int b = i >> 9, c4 = (i & 511)*4;
  *(float4*)&so[(size_t)b*CC + c4] = *(const float4*)&x[((size_t)(b*TT + TT-1))*CC + c4];
}

// ---------- launch ----------
extern "C" void kernel_launch(void* const* d_in, const int* in_sizes, int n_in,
                              void* d_out, int out_size, void* d_ws, size_t ws_size,
                              hipStream_t stream)
{
  const float* x        = (const float*)d_in[0];
  const float* shift_in = (const float*)d_in[1];
  const float* wkv_in   = (const float*)d_in[2];
  const float* v_first  = (const float*)d_in[3];
  const float* x_r = (const float*)d_in[4];
  const float* x_w = (const float*)d_in[5];
  const float* x_k = (const float*)d_in[6];
  const float* x_v = (const float*)d_in[7];
  const float* x_a = (const float*)d_in[8];
  const float* x_g = (const float*)d_in[9];
  const float* w0 = (const float*)d_in[10];
  const float* w1 = (const float*)d_in[11];
  const float* w2 = (const float*)d_in[12];
  const float* a0 = (const float*)d_in[13];
  const float* a1 = (const float*)d_in[14];
  const float* a2 = (const float*)d_in[15];
  const float* v0 = (const float*)d_in[16];
  const float* v1 = (const float*)d_in[17];
  const float* v2 = (const float*)d_in[18];
  const float* g1 = (const float*)d_in[19];
  const float* g2 = (const float*)d_in[20];
  const float* k_k = (const float*)d_in[21];
  const float* k_a = (const float*)d_in[22];
  const float* r_k = (const float*)d_in[23];
  const float* Wr = (const float*)d_in[24];
  const float* Wk = (const float*)d_in[25];
  const float* Wv = (const float*)d_in[26];
  const float* Wo = (const float*)d_in[27];
  const float* ln_w = (const float*)d_in[28];
  const float* ln_b = (const float*)d_in[29];

  // ---- ws layout ----
  char* ws = (char*)d_ws;
  u16* WOB  = (u16*)(ws + 0);
  u16* WRB  = (u16*)(ws + 8388608);   // WRB/WKB/WVB contiguous => fused rkv B
  u16* WKB  = (u16*)(ws + 16777216);
  u16* WVB  = (u16*)(ws + 25165824);
  u16* WCAT = (u16*)(ws + 33554432);
  u16* B2W  = (u16*)(ws + 36175872);
  u16* B2A  = (u16*)(ws + 36700160);
  u16* B2V  = (u16*)(ws + 37224448);
  u16* B2G  = (u16*)(ws + 37748736);
  u16* PBUF = (u16*)(ws + 38797312);
  u16* RB   = (u16*)(ws + 44040192);  // RB/KB/VB contiguous => fused rkv C
  u16* KB   = (u16*)(ws + 60817408);
  u16* VB   = (u16*)(ws + 77594624);
  u16* YB   = (u16*)(ws + 94371840);
  float* DEC  = (float*)(ws + 8388608);     // overlays dead WRB..PBUF (post1 -> scan)
  u16* AO   = (u16*)(ws + 8388608);         // overlays dead DEC (post2 -> final GEMM)

  // ---- d_out scratch ----
  float* out       = (float*)d_out;
  float* shift_out = out + 8388608;
  float* wkv_out   = out + 8396800;
  float* vf_out    = out + 8921088;
  u16* WINb = (u16*)d_out;
  u16* AINb = (u16*)((char*)d_out + 16777216);
  u16* VINb = (u16*)((char*)d_out + 35684352);
  u16* GB   = (u16*)((char*)d_out + 52461568);

  // weight casts
  k_cast<<<4096, 256, 0, stream>>>(Wr, WRB, 4194304);
  k_cast<<<4096, 256, 0, stream>>>(Wk, WKB, 4194304);
  k_cast<<<4096, 256, 0, stream>>>(Wv, WVB, 4194304);
  k_cast<<<4096, 256, 0, stream>>>(Wo, WOB, 4194304);

  // stage-1 fused weight + stage-2 weights
  k_tpad<<<1024, 256, 0, stream>>>(w1, WCAT,            2048,  96, 2048, 128);
  k_tpad<<<1024, 256, 0, stream>>>(a1, WCAT + 128*2048, 2048,  96, 2048, 128);
  k_tpad<<<1024, 256, 0, stream>>>(v1, WCAT + 256*2048, 2048,  64, 2048, 128);
  k_tpad<<<2048, 256, 0, stream>>>(g1, WCAT + 384*2048, 2048, 256, 2048, 256);
  k_tpad<<<1024, 256, 0, stream>>>(w2, B2W,  96, 2048, 128, 2048);
  k_tpad<<<1024, 256, 0, stream>>>(a2, B2A,  96, 2048, 128, 2048);
  k_tpad<<<1024, 256, 0, stream>>>(v2, B2V,  64, 2048, 128, 2048);
  k_tpad<<<2048, 256, 0, stream>>>(g2, B2G, 256, 2048, 256, 2048);

  // fused r/k/v GEMM (single launch; mix + output selected by bx>>4)
  k_gemm<2,1><<<dim3(48,32), 256, 0, stream>>>(nullptr, x, shift_in, x_r, x_k, x_v, x_v,
                                               WRB, nullptr, RB, 2048, 0, 2048, 2048);

  // fused stage-1
  k_gemm<1,2><<<dim3(5,32), 256, 0, stream>>>(nullptr, x, shift_in, x_w, x_a, x_v, x_g,
                                              WCAT, nullptr, PBUF, 2048, 0, 2048, 640);

  // stage-2 GEMMs
  k_gemm<0,1><<<dim3(16,32), 256, 0, stream>>>(PBUF+0,   nullptr,nullptr,nullptr,nullptr,nullptr,nullptr,
                                               B2W, nullptr, WINb, 128, 640, 128, 2048);
  k_gemm<0,1><<<dim3(16,32), 256, 0, stream>>>(PBUF+128, nullptr,nullptr,nullptr,nullptr,nullptr,nullptr,
                                               B2A, nullptr, AINb, 128, 640, 128, 2048);
  k_gemm<0,1><<<dim3(16,32), 256, 0, stream>>>(PBUF+256, nullptr,nullptr,nullptr,nullptr,nullptr,nullptr,
                                               B2V, nullptr, VINb, 128, 640, 128, 2048);
  k_gemm<0,1><<<dim3(16,32), 256, 0, stream>>>(PBUF+384, nullptr,nullptr,nullptr,nullptr,nullptr,nullptr,
                                               B2G, nullptr, GB,   256, 640, 256, 2048);

  // elementwise post
  k_post1<<<32768, 256, 0, stream>>>(KB, VB, WINb, AINb, VINb, v_first,
                                     w0, a0, v0, k_k, k_a, DEC);

  // sequential WKV scan (v4: register-resident, LDS-free, XCD-L2-shared)
  k_scan<<<1024, 64, 0, stream>>>(RB, DEC, KB, VB, VINb, AINb, wkv_in, YB, wkv_out);

  // groupnorm + bonus + gate
  k_post2<<<32768, 256, 0, stream>>>(YB, RB, KB, VB, GB, r_k, ln_w, ln_b, AO);

  // final GEMM -> out
  k_gemm<0,0><<<dim3(16,32), 256, 0, stream>>>(AO, nullptr,nullptr,nullptr,nullptr,nullptr,nullptr,
                                               WOB, out, nullptr, 2048, 2048, 2048, 2048);

  // small outputs last
  k_shift<<<8, 256, 0, stream>>>(x, shift_out);
  hipMemcpyAsync(vf_out, v_first, 33554432, hipMemcpyDeviceToDevice, stream);
}

// Round 8
// 782.542 us; speedup vs baseline: 1.2610x; 1.0776x over previous
//
#include <hip/hip_runtime.h>
#include <hip/hip_bf16.h>
#include <stdint.h>

typedef unsigned short u16;
typedef unsigned int u32;
typedef __attribute__((ext_vector_type(8))) short short8;
typedef __attribute__((ext_vector_type(4))) float f32x4;

#define BB 4
#define TT 1024
#define CC 2048

// ---------- helpers ----------
__device__ __forceinline__ u16 f2bf(float f){
  __hip_bfloat16 h = __float2bfloat16(f);
  return *reinterpret_cast<u16*>(&h);
}
__device__ __forceinline__ float bf2f(u16 h){
  union { u32 u; float f; } v; v.u = ((u32)h) << 16; return v.f;
}

__device__ __forceinline__ void gload16(const void* g, void* s){
  __builtin_amdgcn_global_load_lds((const __attribute__((address_space(1))) u32*)g,
                                   (__attribute__((address_space(3))) u32*)s, 16, 0, 0);
}

__device__ __forceinline__ float wave_sum64(float x){
  #pragma unroll
  for (int m = 1; m < 64; m <<= 1) x += __shfl_xor(x, m, 64);
  return x;
}

template<int N>
__device__ __forceinline__ float ror_add(float x){
  int t = __builtin_amdgcn_update_dpp(0, __builtin_bit_cast(int, x), 0x120 | N, 0xF, 0xF, false);
  return x + __builtin_bit_cast(float, t);
}
__device__ __forceinline__ float red16(float x){
  x = ror_add<8>(x); x = ror_add<4>(x); x = ror_add<2>(x); x = ror_add<1>(x);
  return x;
}

// ---------- fused weight casts: Wr,Wk,Wv,Wo -> bf16 (one launch) ----------
__global__ __launch_bounds__(256) void k_cast4(
  const float* __restrict__ wr, const float* __restrict__ wk,
  const float* __restrict__ wv, const float* __restrict__ wo,
  u16* __restrict__ wsb)
{
  int i = blockIdx.x*256 + threadIdx.x;        // 4,194,304 threads, 4 floats each
  int seg = i >> 20;
  int off = (i & 1048575) * 4;
  const float* src = (seg==0) ? wr : (seg==1) ? wk : (seg==2) ? wv : wo;
  const size_t dofs = (seg==0) ? 4194304u : (seg==1) ? 8388608u : (seg==2) ? 12582912u : 0u;
  float4 v = *(const float4*)&src[off];
  *(ushort4*)&wsb[dofs + off] = make_ushort4(f2bf(v.x), f2bf(v.y), f2bf(v.z), f2bf(v.w));
}

// ---------- fused tiled transposes: 8 matrices, LDS 32x33, coalesced both sides ----------
__global__ __launch_bounds__(256) void k_tpadA(
  const float* __restrict__ w1, const float* __restrict__ a1,
  const float* __restrict__ v1, const float* __restrict__ g1,
  const float* __restrict__ w2, const float* __restrict__ a2,
  const float* __restrict__ v2, const float* __restrict__ g2,
  u16* __restrict__ wsb)
{
  __shared__ float lds[32][33];
  const int blk = blockIdx.x;
  const float* src; int R, S, Rpad, tile, tiles_r; size_t dst;
  if      (blk <  256){ src=w1; R=2048; S=96;   Rpad=2048; dst=16777216u; tile=blk;      tiles_r=64; }
  else if (blk <  512){ src=a1; R=2048; S=96;   Rpad=2048; dst=17039360u; tile=blk-256;  tiles_r=64; }
  else if (blk <  768){ src=v1; R=2048; S=64;   Rpad=2048; dst=17301504u; tile=blk-512;  tiles_r=64; }
  else if (blk < 1280){ src=g1; R=2048; S=256;  Rpad=2048; dst=17563648u; tile=blk-768;  tiles_r=64; }
  else if (blk < 1536){ src=w2; R=96;   S=2048; Rpad=128;  dst=18087936u; tile=blk-1280; tiles_r=4;  }
  else if (blk < 1792){ src=a2; R=96;   S=2048; Rpad=128;  dst=18350080u; tile=blk-1536; tiles_r=4;  }
  else if (blk < 2048){ src=v2; R=64;   S=2048; Rpad=128;  dst=18612224u; tile=blk-1792; tiles_r=4;  }
  else                { src=g2; R=256;  S=2048; Rpad=256;  dst=18874368u; tile=blk-2048; tiles_r=8;  }
  const int tr = tile % tiles_r, ts = tile / tiles_r;
  const int r0 = tr*32, s0 = ts*32;
  const int tj = threadIdx.x & 31, ti = threadIdx.x >> 5;
  #pragma unroll
  for (int p=0;p<4;p++){
    int rr = r0 + p*8 + ti, ss = s0 + tj;
    lds[p*8+ti][tj] = (rr < R && ss < S) ? src[(size_t)rr*S + ss] : 0.f;
  }
  __syncthreads();
  #pragma unroll
  for (int p=0;p<4;p++){
    int sl = p*8 + ti, rl = tj;
    wsb[dst + (size_t)(s0+sl)*Rpad + r0 + rl] = f2bf(lds[rl][sl]);
  }
}

// ---------- GEMM: C[M,N] = A[M,K](bf16) * Bt[N,K]^T(bf16) ----------
// AMODE 0: A via gload_lds, f32 out (final GEMM).
// AMODE 2: on-the-fly token-shift mix; bx<48 => r/k/v (bf16 out); bx 48..52 => stage-1 (act, ldc=640).
// AMODE 3: stage-2 fused: sel=bx>>4 picks A col-offset / B / K / C-offset.
template<int AMODE>
__global__ __launch_bounds__(256) void k_gemm(
  const u16* __restrict__ Abf,
  const float* __restrict__ xg, const float* __restrict__ shiftg,
  const float* __restrict__ mr, const float* __restrict__ mk,
  const float* __restrict__ mv, const float* __restrict__ mw,
  const float* __restrict__ ma, const float* __restrict__ mg,
  const u16* __restrict__ Bt, float* __restrict__ Cf, u16* __restrict__ Cb,
  int K, int lda, int ldb, int ldc)
{
  __shared__ alignas(16) u16 sA[128*32];
  __shared__ alignas(16) u16 sB[128*32];
  const int tid = threadIdx.x;
  const int wv = tid >> 6, ln = tid & 63;
  const int bx = blockIdx.x;
  const int row0 = blockIdx.y * 128;
  const int wr = wv >> 1, wc = wv & 1;

  const float* mixv = nullptr;
  const u16* Ap = Abf;
  const u16* Btp = Bt;
  u16* Cbp = Cb;
  int bcol0 = bx * 128;          // B row-block
  int ccol0 = bx * 128;          // C col
  int ldaa = lda, ldbb = ldb, ldcc = ldc;
  int KK = K, act = 0;

  if (AMODE == 2){
    if (bx < 48){
      int sel = bx >> 4;
      mixv = (sel==0) ? mr : (sel==1) ? mk : mv;
      Cbp = Cb + (size_t)sel * 8388608u;
      ccol0 = (bx & 15) * 128;
      ldcc = 2048;
    } else {
      int sb = bx - 48;
      mixv = (sb==0) ? mw : (sb==1) ? ma : (sb==2) ? mv : mg;
      Cbp = (u16*)Cf;                       // PBUF passed via Cf
      ccol0 = sb * 128;
      ldcc = 640;
      act = (sb==0) ? 1 : (sb>=3 ? 2 : 0);
    }
  }
  if (AMODE == 3){
    int sel = bx >> 4;
    Ap = Abf + sel*128;                     // col offset within 640-wide P row
    Btp = Bt + (size_t)sel * 262144u;
    ldbb = (sel==3) ? 256 : 128;
    KK = (sel==3) ? 256 : 128;
    const int coffs[4] = {0, 8388608, 17842176, 26230784};
    Cbp = Cb + coffs[sel];
    ccol0 = (bx & 15) * 128;
    bcol0 = ccol0;
    ldcc = 2048;
  }

  f32x4 acc[4][4] = {};
  const int ob0 = wv*2048;
  const int o0  = ob0 + ln*16;
  const int rA0 = o0 >> 6;
  const int ke0 = (o0 & 63) >> 1;
  const int ar  = tid >> 2;
  const int akc = (tid & 3) * 8;

  for (int k0 = 0; k0 < KK; k0 += 32){
    __syncthreads();
    if (AMODE != 2){
      gload16(&Ap[(size_t)(row0 + rA0     )*ldaa + k0 + ke0], (void*)((char*)sA + ob0));
      gload16(&Ap[(size_t)(row0 + rA0 + 16)*ldaa + k0 + ke0], (void*)((char*)sA + ob0 + 1024));
    }
    gload16(&Btp[(size_t)(bcol0 + rA0     )*ldbb + k0 + ke0], (void*)((char*)sB + ob0));
    gload16(&Btp[(size_t)(bcol0 + rA0 + 16)*ldbb + k0 + ke0], (void*)((char*)sB + ob0 + 1024));
    if (AMODE == 2){
      float4 m0 = *(const float4*)&mixv[k0 + akc];
      float4 m1 = *(const float4*)&mixv[k0 + akc + 4];
      #pragma unroll
      for (int it = 0; it < 2; ++it){
        int r = ar + it*64;
        int gr = row0 + r;
        size_t xo = (size_t)gr*CC + k0 + akc;
        float4 c0 = *(const float4*)&xg[xo];
        float4 c1 = *(const float4*)&xg[xo + 4];
        const float* pp = ((gr & (TT-1)) == 0) ? &shiftg[(size_t)(gr >> 10)*CC + k0 + akc]
                                               : &xg[xo - CC];
        float4 p0 = *(const float4*)&pp[0];
        float4 p1 = *(const float4*)&pp[4];
        short8 vvv;
        vvv[0] = (short)f2bf(c0.x + (p0.x - c0.x)*m0.x);
        vvv[1] = (short)f2bf(c0.y + (p0.y - c0.y)*m0.y);
        vvv[2] = (short)f2bf(c0.z + (p0.z - c0.z)*m0.z);
        vvv[3] = (short)f2bf(c0.w + (p0.w - c0.w)*m0.w);
        vvv[4] = (short)f2bf(c1.x + (p1.x - c1.x)*m1.x);
        vvv[5] = (short)f2bf(c1.y + (p1.y - c1.y)*m1.y);
        vvv[6] = (short)f2bf(c1.z + (p1.z - c1.z)*m1.z);
        vvv[7] = (short)f2bf(c1.w + (p1.w - c1.w)*m1.w);
        *(short8*)&sA[r*32 + akc] = vvv;
      }
    }
    __syncthreads();
    short8 aF[4], bF[4];
    #pragma unroll
    for (int m=0;m<4;m++) aF[m] = *(const short8*)&sA[(wr*64 + m*16 + (ln&15))*32 + (ln>>4)*8];
    #pragma unroll
    for (int n=0;n<4;n++) bF[n] = *(const short8*)&sB[(wc*64 + n*16 + (ln&15))*32 + (ln>>4)*8];
    #pragma unroll
    for (int m=0;m<4;m++)
      #pragma unroll
      for (int n=0;n<4;n++)
        acc[m][n] = __builtin_amdgcn_mfma_f32_16x16x32_bf16(aF[m], bF[n], acc[m][n], 0,0,0);
  }

  const int cr = (ln >> 4) * 4, ccol = ln & 15;
  #pragma unroll
  for (int m=0;m<4;m++){
    #pragma unroll
    for (int n=0;n<4;n++){
      int gc = ccol0 + wc*64 + n*16 + ccol;
      #pragma unroll
      for (int j=0;j<4;j++){
        int gr = row0 + wr*64 + m*16 + cr + j;
        float v = acc[m][n][j];
        if (AMODE == 0){
          Cf[(size_t)gr*ldcc + gc] = v;
        } else {
          if (act == 1) v = tanhf(v);
          else if (act == 2) v = 1.f/(1.f + expf(-v));
          Cbp[(size_t)gr*ldcc + gc] = f2bf(v);
        }
      }
    }
  }
}

// ---------- post1 ----------
__global__ __launch_bounds__(256) void k_post1(
  u16* __restrict__ kb, u16* __restrict__ vb, const u16* __restrict__ winb,
  u16* __restrict__ ainb, u16* __restrict__ vinb,
  const float* __restrict__ vfirst,
  const float* __restrict__ w0, const float* __restrict__ a0, const float* __restrict__ v0,
  const float* __restrict__ kkv, const float* __restrict__ kav,
  float* __restrict__ dec)
{
  int grp = blockIdx.x*4 + (threadIdx.x >> 6);
  int n = threadIdx.x & 63;
  int i = grp >> 5, h = grp & 31;
  int c = h*64 + n;
  size_t idx = (size_t)i*CC + c;
  float k  = bf2f(kb[idx]),  v = bf2f(vb[idx]);
  float wi = bf2f(winb[idx]), ai = bf2f(ainb[idx]), vi = bf2f(vinb[idx]);
  float vf = vfirst[idx];
  float a  = 1.f/(1.f + expf(-(a0[c] + ai)));
  float z  = -(w0[c] + wi);
  float sp = (z > 15.f) ? z : log1pf(expf(z));
  float decay = expf(-expf(-sp - 0.5f));
  float vg = 1.f/(1.f + expf(-(v0[c] + vi)));
  float vfin = v + (vf - v)*vg;
  float kkr = k * kkv[c];
  float ss = wave_sum64(kkr*kkr);
  float kkn = kkr / fmaxf(sqrtf(ss), 1e-12f);
  float kfin = k * (1.f + (a - 1.f)*kav[c]);
  kb[idx] = f2bf(kfin);
  vb[idx] = f2bf(vfin);
  dec[idx] = decay;
  vinb[idx] = f2bf(kkn);
  ainb[idx] = f2bf(-(kkn * a));   // pre-negated b for the scan
}

// ---------- WKV scan v4 ----------
#define DECL_CHUNK(S) float4 w##S[4]; ushort4 b##S[4], k##S[4], kk##S[4], r##S[4]; u32 v##S[4];

#define SCAN_ISSUE(S, t0) do {                                                   \
  _Pragma("unroll")                                                              \
  for (int s_=0; s_<4; ++s_){                                                    \
    size_t o_ = gc0 + (size_t)((t0)+s_)*CC;                                      \
    w##S[s_]  = *(const float4*)&wb[o_];                                         \
    b##S[s_]  = *(const ushort4*)&bbp[o_];                                       \
    k##S[s_]  = *(const ushort4*)&kb[o_];                                        \
    kk##S[s_] = *(const ushort4*)&kkb[o_];                                       \
    r##S[s_]  = *(const ushort4*)&rb[o_];                                        \
    v##S[s_]  = *(const u32*)&vb[gv0 + (size_t)((t0)+s_)*CC];                    \
  }                                                                              \
} while(0)

#define SCAN_CHUNK(S, t0) do {                                                   \
  _Pragma("unroll")                                                              \
  for (int s_=0; s_<4; ++s_){                                                    \
    const float w_0=w##S[s_].x, w_1=w##S[s_].y, w_2=w##S[s_].z, w_3=w##S[s_].w;  \
    const float b_0=bf2f(b##S[s_].x), b_1=bf2f(b##S[s_].y),                      \
                b_2=bf2f(b##S[s_].z), b_3=bf2f(b##S[s_].w);                      \
    const float k_0=bf2f(k##S[s_].x), k_1=bf2f(k##S[s_].y),                      \
                k_2=bf2f(k##S[s_].z), k_3=bf2f(k##S[s_].w);                      \
    const float q_0=bf2f(kk##S[s_].x), q_1=bf2f(kk##S[s_].y),                    \
                q_2=bf2f(kk##S[s_].z), q_3=bf2f(kk##S[s_].w);                    \
    const float r_0=bf2f(r##S[s_].x), r_1=bf2f(r##S[s_].y),                      \
                r_2=bf2f(r##S[s_].z), r_3=bf2f(r##S[s_].w);                      \
    const u32 vpk_ = v##S[s_];                                                   \
    const float vv0_ = bf2f((u16)(vpk_ & 0xFFFFu));                              \
    const float vv1_ = bf2f((u16)(vpk_ >> 16));                                  \
    float p0_ = fmaf(st[0][0],q_0, st[0][1]*q_1) + fmaf(st[0][2],q_2, st[0][3]*q_3); \
    float p1_ = fmaf(st[1][0],q_0, st[1][1]*q_1) + fmaf(st[1][2],q_2, st[1][3]*q_3); \
    p0_ = red16(p0_); p1_ = red16(p1_);                                          \
    st[0][0] = fmaf(st[0][0],w_0, fmaf(p0_,b_0, vv0_*k_0));                      \
    st[0][1] = fmaf(st[0][1],w_1, fmaf(p0_,b_1, vv0_*k_1));                      \
    st[0][2] = fmaf(st[0][2],w_2, fmaf(p0_,b_2, vv0_*k_2));                      \
    st[0][3] = fmaf(st[0][3],w_3, fmaf(p0_,b_3, vv0_*k_3));                      \
    st[1][0] = fmaf(st[1][0],w_0, fmaf(p1_,b_0, vv1_*k_0));                      \
    st[1][1] = fmaf(st[1][1],w_1, fmaf(p1_,b_1, vv1_*k_1));                      \
    st[1][2] = fmaf(st[1][2],w_2, fmaf(p1_,b_2, vv1_*k_2));                      \
    st[1][3] = fmaf(st[1][3],w_3, fmaf(p1_,b_3, vv1_*k_3));                      \
    float y0_ = fmaf(st[0][0],r_0, st[0][1]*r_1) + fmaf(st[0][2],r_2, st[0][3]*r_3); \
    float y1_ = fmaf(st[1][0],r_0, st[1][1]*r_1) + fmaf(st[1][2],r_2, st[1][3]*r_3); \
    y0_ = red16(y0_); y1_ = red16(y1_);                                          \
    if (cg == 0){                                                                \
      u32 pk_ = (u32)f2bf(y0_) | ((u32)f2bf(y1_) << 16);                         \
      *(u32*)&yb[gv0 + (size_t)((t0)+s_)*CC] = pk_;                              \
    }                                                                            \
  }                                                                              \
} while(0)

__global__ __launch_bounds__(64) void k_scan(
  const u16* __restrict__ rb, const float* __restrict__ wb,
  const u16* __restrict__ kb, const u16* __restrict__ vb,
  const u16* __restrict__ kkb, const u16* __restrict__ bbp,
  const float* __restrict__ wkv_in, u16* __restrict__ yb, float* __restrict__ wkv_out)
{
  const int blk = blockIdx.x;
  const int bh = blk & 127, oct = blk >> 7;
  const int b = bh >> 5, h = bh & 31;
  const int ln = threadIdx.x;
  const int rg = ln >> 4;
  const int cg = ln & 15;
  const int row0 = oct*8 + rg*2;
  const int col0 = cg*4;

  float st[2][4];
  {
    const float* sp0 = &wkv_in[((size_t)bh*64 + row0    )*64 + col0];
    const float* sp1 = &wkv_in[((size_t)bh*64 + row0 + 1)*64 + col0];
    float4 a = *(const float4*)sp0, c = *(const float4*)sp1;
    st[0][0]=a.x; st[0][1]=a.y; st[0][2]=a.z; st[0][3]=a.w;
    st[1][0]=c.x; st[1][1]=c.y; st[1][2]=c.z; st[1][3]=c.w;
  }

  const size_t gc0 = ((size_t)b*TT)*CC + h*64 + col0;
  const size_t gv0 = ((size_t)b*TT)*CC + h*64 + row0;

  DECL_CHUNK(A) DECL_CHUNK(B) DECL_CHUNK(C) DECL_CHUNK(D)

  SCAN_ISSUE(A, 0);
  SCAN_ISSUE(B, 4);
  SCAN_ISSUE(C, 8);
  for (int it = 0; it < 64; ++it){
    const int t0 = it*16;
    if (t0+12 < TT) SCAN_ISSUE(D, t0+12);
    SCAN_CHUNK(A, t0);
    if (t0+16 < TT) SCAN_ISSUE(A, t0+16);
    SCAN_CHUNK(B, t0+4);
    if (t0+20 < TT) SCAN_ISSUE(B, t0+20);
    SCAN_CHUNK(C, t0+8);
    if (t0+24 < TT) SCAN_ISSUE(C, t0+24);
    SCAN_CHUNK(D, t0+12);
  }

  {
    float* wo0 = &wkv_out[((size_t)bh*64 + row0    )*64 + col0];
    float* wo1 = &wkv_out[((size_t)bh*64 + row0 + 1)*64 + col0];
    *(float4*)wo0 = make_float4(st[0][0], st[0][1], st[0][2], st[0][3]);
    *(float4*)wo1 = make_float4(st[1][0], st[1][1], st[1][2], st[1][3]);
  }
}

// ---------- post2 ----------
__global__ __launch_bounds__(256) void k_post2(
  const u16* __restrict__ ybuf, const u16* __restrict__ rbuf,
  const u16* __restrict__ kfb, const u16* __restrict__ vfb,
  const u16* __restrict__ gbuf, const float* __restrict__ rk,
  const float* __restrict__ lnw, const float* __restrict__ lnb, u16* __restrict__ ao)
{
  int grp = blockIdx.x*4 + (threadIdx.x >> 6);
  int n = threadIdx.x & 63;
  int i = grp >> 5, h = grp & 31;
  int c = h*64 + n;
  size_t idx = (size_t)i*CC + c;
  float y = bf2f(ybuf[idx]);
  float s1 = wave_sum64(y);
  float s2 = wave_sum64(y*y);
  float mu = s1 * (1.f/64.f);
  float var = s2 * (1.f/64.f) - mu*mu;
  float yn = (y - mu) * rsqrtf(var + 6.4e-4f) * lnw[c] + lnb[c];
  float rv = bf2f(rbuf[idx]), kv = bf2f(kfb[idx]);
  float s3 = wave_sum64(rv * kv * rk[c]);
  float bonus = s3 * bf2f(vfb[idx]);
  ao[idx] = f2bf((yn + bonus) * bf2f(gbuf[idx]));
}

// ---------- shift_state_out = x[:, -1] ----------
__global__ __launch_bounds__(256) void k_shift(const float* __restrict__ x, float* __restrict__ so){
  int i = blockIdx.x*256 + threadIdx.x;
  int b = i >> 9, c4 = (i & 511)*4;
  *(float4*)&so[(size_t)b*CC + c4] = *(const float4*)&x[((size_t)(b*TT + TT-1))*CC + c4];
}

// ---------- launch ----------
extern "C" void kernel_launch(void* const* d_in, const int* in_sizes, int n_in,
                              void* d_out, int out_size, void* d_ws, size_t ws_size,
                              hipStream_t stream)
{
  const float* x        = (const float*)d_in[0];
  const float* shift_in = (const float*)d_in[1];
  const float* wkv_in   = (const float*)d_in[2];
  const float* v_first  = (const float*)d_in[3];
  const float* x_r = (const float*)d_in[4];
  const float* x_w = (const float*)d_in[5];
  const float* x_k = (const float*)d_in[6];
  const float* x_v = (const float*)d_in[7];
  const float* x_a = (const float*)d_in[8];
  const float* x_g = (const float*)d_in[9];
  const float* w0 = (const float*)d_in[10];
  const float* w1 = (const float*)d_in[11];
  const float* w2 = (const float*)d_in[12];
  const float* a0 = (const float*)d_in[13];
  const float* a1 = (const float*)d_in[14];
  const float* a2 = (const float*)d_in[15];
  const float* v0 = (const float*)d_in[16];
  const float* v1 = (const float*)d_in[17];
  const float* v2 = (const float*)d_in[18];
  const float* g1 = (const float*)d_in[19];
  const float* g2 = (const float*)d_in[20];
  const float* k_k = (const float*)d_in[21];
  const float* k_a = (const float*)d_in[22];
  const float* r_k = (const float*)d_in[23];
  const float* Wr = (const float*)d_in[24];
  const float* Wk = (const float*)d_in[25];
  const float* Wv = (const float*)d_in[26];
  const float* Wo = (const float*)d_in[27];
  const float* ln_w = (const float*)d_in[28];
  const float* ln_b = (const float*)d_in[29];

  // ---- ws layout (offsets consumed by k_cast4/k_tpadA as elem offsets) ----
  char* ws = (char*)d_ws;
  u16* WOB  = (u16*)(ws + 0);
  u16* WRB  = (u16*)(ws + 8388608);   // WRB/WKB/WVB/WCAT contiguous (B rows 0..6783)
  u16* B2W  = (u16*)(ws + 36175872);  // B2W/B2A/B2V/B2G contiguous, stride 262144 elems
  u16* PBUF = (u16*)(ws + 38797312);
  u16* RB   = (u16*)(ws + 44040192);  // RB/KB/VB contiguous, stride 8388608 elems
  u16* KB   = (u16*)(ws + 60817408);
  u16* VB   = (u16*)(ws + 77594624);
  u16* YB   = (u16*)(ws + 94371840);
  float* DEC  = (float*)(ws + 8388608);   // overlays dead WRB..PBUF (post1 -> scan)
  u16* AO   = (u16*)(ws + 8388608);       // overlays dead DEC (post2 -> final GEMM)

  // ---- d_out scratch ----
  float* out       = (float*)d_out;
  float* shift_out = out + 8388608;
  float* wkv_out   = out + 8396800;
  float* vf_out    = out + 8921088;
  u16* WINb = (u16*)d_out;
  u16* AINb = (u16*)((char*)d_out + 16777216);
  u16* VINb = (u16*)((char*)d_out + 35684352);

  // weight prep (2 launches)
  k_cast4<<<16384, 256, 0, stream>>>(Wr, Wk, Wv, Wo, (u16*)ws);
  k_tpadA<<<2560, 256, 0, stream>>>(w1, a1, v1, g1, w2, a2, v2, g2, (u16*)ws);

  // fused r/k/v + stage-1 GEMM (single launch, 53x32)
  k_gemm<2><<<dim3(53,32), 256, 0, stream>>>(nullptr, x, shift_in,
                                             x_r, x_k, x_v, x_w, x_a, x_g,
                                             WRB, (float*)PBUF, RB, 2048, 0, 2048, 2048);

  // fused stage-2 GEMMs (single launch, 64x32)
  k_gemm<3><<<dim3(64,32), 256, 0, stream>>>(PBUF, nullptr, nullptr,
                                             nullptr, nullptr, nullptr, nullptr, nullptr, nullptr,
                                             B2W, nullptr, (u16*)d_out, 0, 640, 128, 2048);

  // elementwise post
  k_post1<<<32768, 256, 0, stream>>>(KB, VB, WINb, AINb, VINb, v_first,
                                     w0, a0, v0, k_k, k_a, DEC);

  // sequential WKV scan (v4)
  k_scan<<<1024, 64, 0, stream>>>(RB, DEC, KB, VB, VINb, AINb, wkv_in, YB, wkv_out);

  // groupnorm + bonus + gate
  k_post2<<<32768, 256, 0, stream>>>(YB, RB, KB, VB, (u16*)((char*)d_out + 52461568),
                                     r_k, ln_w, ln_b, AO);

  // final GEMM -> out
  k_gemm<0><<<dim3(16,32), 256, 0, stream>>>(AO, nullptr, nullptr,
                                             nullptr, nullptr, nullptr, nullptr, nullptr, nullptr,
                                             WOB, out, nullptr, 2048, 2048, 2048, 2048);

  // small outputs last
  k_shift<<<8, 256, 0, stream>>>(x, shift_out);
  hipMemcpyAsync(vf_out, v_first, 33554432, hipMemcpyDeviceToDevice, stream);
}

// Round 9
// 761.602 us; speedup vs baseline: 1.2956x; 1.0275x over previous
//
#include <hip/hip_runtime.h>
#include <hip/hip_bf16.h>
#include <stdint.h>

typedef unsigned short u16;
typedef unsigned int u32;
typedef __attribute__((ext_vector_type(8))) short short8;
typedef __attribute__((ext_vector_type(4))) float f32x4;

#define BB 4
#define TT 1024
#define CC 2048

// ---------- helpers ----------
__device__ __forceinline__ u16 f2bf(float f){
  __hip_bfloat16 h = __float2bfloat16(f);
  return *reinterpret_cast<u16*>(&h);
}
__device__ __forceinline__ float bf2f(u16 h){
  union { u32 u; float f; } v; v.u = ((u32)h) << 16; return v.f;
}

__device__ __forceinline__ void gload16(const void* g, void* s){
  __builtin_amdgcn_global_load_lds((const __attribute__((address_space(1))) u32*)g,
                                   (__attribute__((address_space(3))) u32*)s, 16, 0, 0);
}

__device__ __forceinline__ float wave_sum64(float x){
  #pragma unroll
  for (int m = 1; m < 64; m <<= 1) x += __shfl_xor(x, m, 64);
  return x;
}

template<int N>
__device__ __forceinline__ float ror_add(float x){
  int t = __builtin_amdgcn_update_dpp(0, __builtin_bit_cast(int, x), 0x120 | N, 0xF, 0xF, false);
  return x + __builtin_bit_cast(float, t);
}
__device__ __forceinline__ float red16(float x){
  x = ror_add<8>(x); x = ror_add<4>(x); x = ror_add<2>(x); x = ror_add<1>(x);
  return x;
}

// ---------- fused weight casts: Wr,Wk,Wv,Wo -> bf16 (one launch) ----------
__global__ __launch_bounds__(256) void k_cast4(
  const float* __restrict__ wr, const float* __restrict__ wk,
  const float* __restrict__ wv, const float* __restrict__ wo,
  u16* __restrict__ wsb)
{
  int i = blockIdx.x*256 + threadIdx.x;
  int seg = i >> 20;
  int off = (i & 1048575) * 4;
  const float* src = (seg==0) ? wr : (seg==1) ? wk : (seg==2) ? wv : wo;
  const size_t dofs = (seg==0) ? 4194304u : (seg==1) ? 8388608u : (seg==2) ? 12582912u : 0u;
  float4 v = *(const float4*)&src[off];
  *(ushort4*)&wsb[dofs + off] = make_ushort4(f2bf(v.x), f2bf(v.y), f2bf(v.z), f2bf(v.w));
}

// ---------- fused tiled transposes: 8 matrices, LDS 32x33 ----------
__global__ __launch_bounds__(256) void k_tpadA(
  const float* __restrict__ w1, const float* __restrict__ a1,
  const float* __restrict__ v1, const float* __restrict__ g1,
  const float* __restrict__ w2, const float* __restrict__ a2,
  const float* __restrict__ v2, const float* __restrict__ g2,
  u16* __restrict__ wsb)
{
  __shared__ float lds[32][33];
  const int blk = blockIdx.x;
  const float* src; int R, S, Rpad, tile, tiles_r; size_t dst;
  if      (blk <  256){ src=w1; R=2048; S=96;   Rpad=2048; dst=16777216u; tile=blk;      tiles_r=64; }
  else if (blk <  512){ src=a1; R=2048; S=96;   Rpad=2048; dst=17039360u; tile=blk-256;  tiles_r=64; }
  else if (blk <  768){ src=v1; R=2048; S=64;   Rpad=2048; dst=17301504u; tile=blk-512;  tiles_r=64; }
  else if (blk < 1280){ src=g1; R=2048; S=256;  Rpad=2048; dst=17563648u; tile=blk-768;  tiles_r=64; }
  else if (blk < 1536){ src=w2; R=96;   S=2048; Rpad=128;  dst=18087936u; tile=blk-1280; tiles_r=4;  }
  else if (blk < 1792){ src=a2; R=96;   S=2048; Rpad=128;  dst=18350080u; tile=blk-1536; tiles_r=4;  }
  else if (blk < 2048){ src=v2; R=64;   S=2048; Rpad=128;  dst=18612224u; tile=blk-1792; tiles_r=4;  }
  else                { src=g2; R=256;  S=2048; Rpad=256;  dst=18874368u; tile=blk-2048; tiles_r=8;  }
  const int tr = tile % tiles_r, ts = tile / tiles_r;
  const int r0 = tr*32, s0 = ts*32;
  const int tj = threadIdx.x & 31, ti = threadIdx.x >> 5;
  #pragma unroll
  for (int p=0;p<4;p++){
    int rr = r0 + p*8 + ti, ss = s0 + tj;
    lds[p*8+ti][tj] = (rr < R && ss < S) ? src[(size_t)rr*S + ss] : 0.f;
  }
  __syncthreads();
  #pragma unroll
  for (int p=0;p<4;p++){
    int sl = p*8 + ti, rl = tj;
    wsb[dst + (size_t)(s0+sl)*Rpad + r0 + rl] = f2bf(lds[rl][sl]);
  }
}

// ---------- prep: token-shift mix -> XR,XK,XV,XW bf16 (one pass over x) ----------
__global__ __launch_bounds__(256) void k_prep4(
  const float* __restrict__ x, const float* __restrict__ shift_in,
  const float* __restrict__ mr, const float* __restrict__ mk,
  const float* __restrict__ mv, const float* __restrict__ mw,
  u16* __restrict__ xr, u16* __restrict__ xk, u16* __restrict__ xv, u16* __restrict__ xw)
{
  int idx = blockIdx.x*256 + threadIdx.x;       // 2,097,152 threads x 4 elems
  int c4 = (idx & 511) * 4;
  int t  = (idx >> 9) & (TT-1);
  int b  = idx >> 19;
  size_t xo = ((size_t)(b*TT + t))*CC + c4;
  float4 xc = *(const float4*)&x[xo];
  float4 xp = (t == 0) ? *(const float4*)&shift_in[(size_t)b*CC + c4]
                       : *(const float4*)&x[xo - CC];
  float d0 = xp.x-xc.x, d1 = xp.y-xc.y, d2 = xp.z-xc.z, d3 = xp.w-xc.w;
#define MIXO(mp, op) { float4 m = *(const float4*)&mp[c4]; \
    *(ushort4*)&op[xo] = make_ushort4(f2bf(fmaf(d0,m.x,xc.x)), f2bf(fmaf(d1,m.y,xc.y)), \
                                      f2bf(fmaf(d2,m.z,xc.z)), f2bf(fmaf(d3,m.w,xc.w))); }
  MIXO(mr, xr); MIXO(mk, xk); MIXO(mv, xv); MIXO(mw, xw);
#undef MIXO
}

// ---------- GEMM: C[M,N] = A[M,K](bf16) * Bt[N,K]^T(bf16) ----------
// AMODE 0: A via gload_lds, f32 out (final GEMM).
// AMODE 2: fused rkv+stage1. Abf = XR (XK,XV at +8M,+16M; XW at +24M elems).
//          bx<48: rkv, gload A. bx=48(w)/50(v): gload A. bx=49(a)/51/52(g): on-the-fly mix.
// AMODE 3: stage-2 fused: sel=bx>>4 picks A col-offset / B / K / C-offset.
template<int AMODE>
__global__ __launch_bounds__(256) void k_gemm(
  const u16* __restrict__ Abf,
  const float* __restrict__ xg, const float* __restrict__ shiftg,
  const float* __restrict__ ma, const float* __restrict__ mg,
  const u16* __restrict__ Bt, float* __restrict__ Cf, u16* __restrict__ Cb,
  int K, int lda, int ldb, int ldc)
{
  __shared__ alignas(16) u16 sA[128*32];
  __shared__ alignas(16) u16 sB[128*32];
  const int tid = threadIdx.x;
  const int wv = tid >> 6, ln = tid & 63;
  const int bx = blockIdx.x;
  const int row0 = blockIdx.y * 128;
  const int wr = wv >> 1, wc = wv & 1;

  const float* mixv = nullptr;
  const u16* Ap = Abf;
  const u16* Btp = Bt;
  u16* Cbp = Cb;
  bool bmix = false;
  int bcol0 = bx * 128;
  int ccol0 = bx * 128;
  int ldaa = lda, ldbb = ldb, ldcc = ldc;
  int KK = K, act = 0;

  if (AMODE == 2){
    if (bx < 48){
      int sel = bx >> 4;
      Ap = Abf + (size_t)sel * 8388608u;
      Cbp = Cb + (size_t)sel * 8388608u;
      ccol0 = (bx & 15) * 128;
      ldcc = 2048; ldaa = 2048;
    } else {
      int sb = bx - 48;
      Cbp = (u16*)Cf;                       // PBUF via Cf
      ccol0 = sb * 128;
      ldcc = 640;
      act = (sb==0) ? 1 : (sb>=3 ? 2 : 0);
      if (sb == 0){ Ap = Abf + 25165824u; ldaa = 2048; }        // XW
      else if (sb == 2){ Ap = Abf + 16777216u; ldaa = 2048; }   // XV
      else { bmix = true; mixv = (sb==1) ? ma : mg; }
    }
  }
  if (AMODE == 3){
    int sel = bx >> 4;
    Ap = Abf + sel*128;
    Btp = Bt + (size_t)sel * 262144u;
    ldbb = (sel==3) ? 256 : 128;
    KK = (sel==3) ? 256 : 128;
    const int coffs[4] = {0, 8388608, 17842176, 26230784};
    Cbp = Cb + coffs[sel];
    ccol0 = (bx & 15) * 128;
    bcol0 = ccol0;
    ldcc = 2048;
  }

  f32x4 acc[4][4] = {};
  const int ob0 = wv*2048;
  const int o0  = ob0 + ln*16;
  const int rA0 = o0 >> 6;
  const int ke0 = (o0 & 63) >> 1;
  const int ar  = tid >> 2;
  const int akc = (tid & 3) * 8;

  for (int k0 = 0; k0 < KK; k0 += 32){
    __syncthreads();
    if (AMODE != 2 || !bmix){
      gload16(&Ap[(size_t)(row0 + rA0     )*ldaa + k0 + ke0], (void*)((char*)sA + ob0));
      gload16(&Ap[(size_t)(row0 + rA0 + 16)*ldaa + k0 + ke0], (void*)((char*)sA + ob0 + 1024));
    }
    gload16(&Btp[(size_t)(bcol0 + rA0     )*ldbb + k0 + ke0], (void*)((char*)sB + ob0));
    gload16(&Btp[(size_t)(bcol0 + rA0 + 16)*ldbb + k0 + ke0], (void*)((char*)sB + ob0 + 1024));
    if (AMODE == 2 && bmix){
      float4 m0 = *(const float4*)&mixv[k0 + akc];
      float4 m1 = *(const float4*)&mixv[k0 + akc + 4];
      #pragma unroll
      for (int it = 0; it < 2; ++it){
        int r = ar + it*64;
        int gr = row0 + r;
        size_t xo = (size_t)gr*CC + k0 + akc;
        float4 c0 = *(const float4*)&xg[xo];
        float4 c1 = *(const float4*)&xg[xo + 4];
        const float* pp = ((gr & (TT-1)) == 0) ? &shiftg[(size_t)(gr >> 10)*CC + k0 + akc]
                                               : &xg[xo - CC];
        float4 p0 = *(const float4*)&pp[0];
        float4 p1 = *(const float4*)&pp[4];
        short8 vvv;
        vvv[0] = (short)f2bf(c0.x + (p0.x - c0.x)*m0.x);
        vvv[1] = (short)f2bf(c0.y + (p0.y - c0.y)*m0.y);
        vvv[2] = (short)f2bf(c0.z + (p0.z - c0.z)*m0.z);
        vvv[3] = (short)f2bf(c0.w + (p0.w - c0.w)*m0.w);
        vvv[4] = (short)f2bf(c1.x + (p1.x - c1.x)*m1.x);
        vvv[5] = (short)f2bf(c1.y + (p1.y - c1.y)*m1.y);
        vvv[6] = (short)f2bf(c1.z + (p1.z - c1.z)*m1.z);
        vvv[7] = (short)f2bf(c1.w + (p1.w - c1.w)*m1.w);
        *(short8*)&sA[r*32 + akc] = vvv;
      }
    }
    __syncthreads();
    short8 aF[4], bF[4];
    #pragma unroll
    for (int m=0;m<4;m++) aF[m] = *(const short8*)&sA[(wr*64 + m*16 + (ln&15))*32 + (ln>>4)*8];
    #pragma unroll
    for (int n=0;n<4;n++) bF[n] = *(const short8*)&sB[(wc*64 + n*16 + (ln&15))*32 + (ln>>4)*8];
    #pragma unroll
    for (int m=0;m<4;m++)
      #pragma unroll
      for (int n=0;n<4;n++)
        acc[m][n] = __builtin_amdgcn_mfma_f32_16x16x32_bf16(aF[m], bF[n], acc[m][n], 0,0,0);
  }

  const int cr = (ln >> 4) * 4, ccol = ln & 15;
  #pragma unroll
  for (int m=0;m<4;m++){
    #pragma unroll
    for (int n=0;n<4;n++){
      int gc = ccol0 + wc*64 + n*16 + ccol;
      #pragma unroll
      for (int j=0;j<4;j++){
        int gr = row0 + wr*64 + m*16 + cr + j;
        float v = acc[m][n][j];
        if (AMODE == 0){
          Cf[(size_t)gr*ldcc + gc] = v;
        } else {
          if (act == 1) v = tanhf(v);
          else if (act == 2) v = 1.f/(1.f + expf(-v));
          Cbp[(size_t)gr*ldcc + gc] = f2bf(v);
        }
      }
    }
  }
}

// ---------- post1 ----------
__global__ __launch_bounds__(256) void k_post1(
  u16* __restrict__ kb, u16* __restrict__ vb, const u16* __restrict__ winb,
  u16* __restrict__ ainb, u16* __restrict__ vinb,
  const float* __restrict__ vfirst,
  const float* __restrict__ w0, const float* __restrict__ a0, const float* __restrict__ v0,
  const float* __restrict__ kkv, const float* __restrict__ kav,
  float* __restrict__ dec)
{
  int grp = blockIdx.x*4 + (threadIdx.x >> 6);
  int n = threadIdx.x & 63;
  int i = grp >> 5, h = grp & 31;
  int c = h*64 + n;
  size_t idx = (size_t)i*CC + c;
  float k  = bf2f(kb[idx]),  v = bf2f(vb[idx]);
  float wi = bf2f(winb[idx]), ai = bf2f(ainb[idx]), vi = bf2f(vinb[idx]);
  float vf = vfirst[idx];
  float a  = 1.f/(1.f + expf(-(a0[c] + ai)));
  float z  = -(w0[c] + wi);
  float sp = (z > 15.f) ? z : log1pf(expf(z));
  float decay = expf(-expf(-sp - 0.5f));
  float vg = 1.f/(1.f + expf(-(v0[c] + vi)));
  float vfin = v + (vf - v)*vg;
  float kkr = k * kkv[c];
  float ss = wave_sum64(kkr*kkr);
  float kkn = kkr / fmaxf(sqrtf(ss), 1e-12f);
  float kfin = k * (1.f + (a - 1.f)*kav[c]);
  kb[idx] = f2bf(kfin);
  vb[idx] = f2bf(vfin);
  dec[idx] = decay;
  vinb[idx] = f2bf(kkn);
  ainb[idx] = f2bf(-(kkn * a));
}

// ---------- WKV scan v4 ----------
#define DECL_CHUNK(S) float4 w##S[4]; ushort4 b##S[4], k##S[4], kk##S[4], r##S[4]; u32 v##S[4];

#define SCAN_ISSUE(S, t0) do {                                                   \
  _Pragma("unroll")                                                              \
  for (int s_=0; s_<4; ++s_){                                                    \
    size_t o_ = gc0 + (size_t)((t0)+s_)*CC;                                      \
    w##S[s_]  = *(const float4*)&wb[o_];                                         \
    b##S[s_]  = *(const ushort4*)&bbp[o_];                                       \
    k##S[s_]  = *(const ushort4*)&kb[o_];                                        \
    kk##S[s_] = *(const ushort4*)&kkb[o_];                                       \
    r##S[s_]  = *(const ushort4*)&rb[o_];                                        \
    v##S[s_]  = *(const u32*)&vb[gv0 + (size_t)((t0)+s_)*CC];                    \
  }                                                                              \
} while(0)

#define SCAN_CHUNK(S, t0) do {                                                   \
  _Pragma("unroll")                                                              \
  for (int s_=0; s_<4; ++s_){                                                    \
    const float w_0=w##S[s_].x, w_1=w##S[s_].y, w_2=w##S[s_].z, w_3=w##S[s_].w;  \
    const float b_0=bf2f(b##S[s_].x), b_1=bf2f(b##S[s_].y),                      \
                b_2=bf2f(b##S[s_].z), b_3=bf2f(b##S[s_].w);                      \
    const float k_0=bf2f(k##S[s_].x), k_1=bf2f(k##S[s_].y),                      \
                k_2=bf2f(k##S[s_].z), k_3=bf2f(k##S[s_].w);                      \
    const float q_0=bf2f(kk##S[s_].x), q_1=bf2f(kk##S[s_].y),                    \
                q_2=bf2f(kk##S[s_].z), q_3=bf2f(kk##S[s_].w);                    \
    const float r_0=bf2f(r##S[s_].x), r_1=bf2f(r##S[s_].y),                      \
                r_2=bf2f(r##S[s_].z), r_3=bf2f(r##S[s_].w);                      \
    const u32 vpk_ = v##S[s_];                                                   \
    const float vv0_ = bf2f((u16)(vpk_ & 0xFFFFu));                              \
    const float vv1_ = bf2f((u16)(vpk_ >> 16));                                  \
    float p0_ = fmaf(st[0][0],q_0, st[0][1]*q_1) + fmaf(st[0][2],q_2, st[0][3]*q_3); \
    float p1_ = fmaf(st[1][0],q_0, st[1][1]*q_1) + fmaf(st[1][2],q_2, st[1][3]*q_3); \
    p0_ = red16(p0_); p1_ = red16(p1_);                                          \
    st[0][0] = fmaf(st[0][0],w_0, fmaf(p0_,b_0, vv0_*k_0));                      \
    st[0][1] = fmaf(st[0][1],w_1, fmaf(p0_,b_1, vv0_*k_1));                      \
    st[0][2] = fmaf(st[0][2],w_2, fmaf(p0_,b_2, vv0_*k_2));                      \
    st[0][3] = fmaf(st[0][3],w_3, fmaf(p0_,b_3, vv0_*k_3));                      \
    st[1][0] = fmaf(st[1][0],w_0, fmaf(p1_,b_0, vv1_*k_0));                      \
    st[1][1] = fmaf(st[1][1],w_1, fmaf(p1_,b_1, vv1_*k_1));                      \
    st[1][2] = fmaf(st[1][2],w_2, fmaf(p1_,b_2, vv1_*k_2));                      \
    st[1][3] = fmaf(st[1][3],w_3, fmaf(p1_,b_3, vv1_*k_3));                      \
    float y0_ = fmaf(st[0][0],r_0, st[0][1]*r_1) + fmaf(st[0][2],r_2, st[0][3]*r_3); \
    float y1_ = fmaf(st[1][0],r_0, st[1][1]*r_1) + fmaf(st[1][2],r_2, st[1][3]*r_3); \
    y0_ = red16(y0_); y1_ = red16(y1_);                                          \
    if (cg == 0){                                                                \
      u32 pk_ = (u32)f2bf(y0_) | ((u32)f2bf(y1_) << 16);                         \
      *(u32*)&yb[gv0 + (size_t)((t0)+s_)*CC] = pk_;                              \
    }                                                                            \
  }                                                                              \
} while(0)

__global__ __launch_bounds__(64) void k_scan(
  const u16* __restrict__ rb, const float* __restrict__ wb,
  const u16* __restrict__ kb, const u16* __restrict__ vb,
  const u16* __restrict__ kkb, const u16* __restrict__ bbp,
  const float* __restrict__ wkv_in, u16* __restrict__ yb, float* __restrict__ wkv_out)
{
  const int blk = blockIdx.x;
  const int bh = blk & 127, oct = blk >> 7;
  const int b = bh >> 5, h = bh & 31;
  const int ln = threadIdx.x;
  const int rg = ln >> 4;
  const int cg = ln & 15;
  const int row0 = oct*8 + rg*2;
  const int col0 = cg*4;

  float st[2][4];
  {
    const float* sp0 = &wkv_in[((size_t)bh*64 + row0    )*64 + col0];
    const float* sp1 = &wkv_in[((size_t)bh*64 + row0 + 1)*64 + col0];
    float4 a = *(const float4*)sp0, c = *(const float4*)sp1;
    st[0][0]=a.x; st[0][1]=a.y; st[0][2]=a.z; st[0][3]=a.w;
    st[1][0]=c.x; st[1][1]=c.y; st[1][2]=c.z; st[1][3]=c.w;
  }

  const size_t gc0 = ((size_t)b*TT)*CC + h*64 + col0;
  const size_t gv0 = ((size_t)b*TT)*CC + h*64 + row0;

  DECL_CHUNK(A) DECL_CHUNK(B) DECL_CHUNK(C) DECL_CHUNK(D)

  SCAN_ISSUE(A, 0);
  SCAN_ISSUE(B, 4);
  SCAN_ISSUE(C, 8);
  for (int it = 0; it < 64; ++it){
    const int t0 = it*16;
    if (t0+12 < TT) SCAN_ISSUE(D, t0+12);
    SCAN_CHUNK(A, t0);
    if (t0+16 < TT) SCAN_ISSUE(A, t0+16);
    SCAN_CHUNK(B, t0+4);
    if (t0+20 < TT) SCAN_ISSUE(B, t0+20);
    SCAN_CHUNK(C, t0+8);
    if (t0+24 < TT) SCAN_ISSUE(C, t0+24);
    SCAN_CHUNK(D, t0+12);
  }

  {
    float* wo0 = &wkv_out[((size_t)bh*64 + row0    )*64 + col0];
    float* wo1 = &wkv_out[((size_t)bh*64 + row0 + 1)*64 + col0];
    *(float4*)wo0 = make_float4(st[0][0], st[0][1], st[0][2], st[0][3]);
    *(float4*)wo1 = make_float4(st[1][0], st[1][1], st[1][2], st[1][3]);
  }
}

// ---------- post2 ----------
__global__ __launch_bounds__(256) void k_post2(
  const u16* __restrict__ ybuf, const u16* __restrict__ rbuf,
  const u16* __restrict__ kfb, const u16* __restrict__ vfb,
  const u16* __restrict__ gbuf, const float* __restrict__ rk,
  const float* __restrict__ lnw, const float* __restrict__ lnb, u16* __restrict__ ao)
{
  int grp = blockIdx.x*4 + (threadIdx.x >> 6);
  int n = threadIdx.x & 63;
  int i = grp >> 5, h = grp & 31;
  int c = h*64 + n;
  size_t idx = (size_t)i*CC + c;
  float y = bf2f(ybuf[idx]);
  float s1 = wave_sum64(y);
  float s2 = wave_sum64(y*y);
  float mu = s1 * (1.f/64.f);
  float var = s2 * (1.f/64.f) - mu*mu;
  float yn = (y - mu) * rsqrtf(var + 6.4e-4f) * lnw[c] + lnb[c];
  float rv = bf2f(rbuf[idx]), kv = bf2f(kfb[idx]);
  float s3 = wave_sum64(rv * kv * rk[c]);
  float bonus = s3 * bf2f(vfb[idx]);
  ao[idx] = f2bf((yn + bonus) * bf2f(gbuf[idx]));
}

// ---------- shift_state_out = x[:, -1] ----------
__global__ __launch_bounds__(256) void k_shift(const float* __restrict__ x, float* __restrict__ so){
  int i = blockIdx.x*256 + threadIdx.x;
  int b = i >> 9, c4 = (i & 511)*4;
  *(float4*)&so[(size_t)b*CC + c4] = *(const float4*)&x[((size_t)(b*TT + TT-1))*CC + c4];
}

// ---------- launch ----------
extern "C" void kernel_launch(void* const* d_in, const int* in_sizes, int n_in,
                              void* d_out, int out_size, void* d_ws, size_t ws_size,
                              hipStream_t stream)
{
  const float* x        = (const float*)d_in[0];
  const float* shift_in = (const float*)d_in[1];
  const float* wkv_in   = (const float*)d_in[2];
  const float* v_first  = (const float*)d_in[3];
  const float* x_r = (const float*)d_in[4];
  const float* x_w = (const float*)d_in[5];
  const float* x_k = (const float*)d_in[6];
  const float* x_v = (const float*)d_in[7];
  const float* x_a = (const float*)d_in[8];
  const float* x_g = (const float*)d_in[9];
  const float* w0 = (const float*)d_in[10];
  const float* w1 = (const float*)d_in[11];
  const float* w2 = (const float*)d_in[12];
  const float* a0 = (const float*)d_in[13];
  const float* a1 = (const float*)d_in[14];
  const float* a2 = (const float*)d_in[15];
  const float* v0 = (const float*)d_in[16];
  const float* v1 = (const float*)d_in[17];
  const float* v2 = (const float*)d_in[18];
  const float* g1 = (const float*)d_in[19];
  const float* g2 = (const float*)d_in[20];
  const float* k_k = (const float*)d_in[21];
  const float* k_a = (const float*)d_in[22];
  const float* r_k = (const float*)d_in[23];
  const float* Wr = (const float*)d_in[24];
  const float* Wk = (const float*)d_in[25];
  const float* Wv = (const float*)d_in[26];
  const float* Wo = (const float*)d_in[27];
  const float* ln_w = (const float*)d_in[28];
  const float* ln_b = (const float*)d_in[29];

  // ---- ws layout ----
  char* ws = (char*)d_ws;
  u16* WOB  = (u16*)(ws + 0);
  u16* WRB  = (u16*)(ws + 8388608);   // WRB/WKB/WVB/WCAT contiguous (B rows 0..6783)
  u16* B2W  = (u16*)(ws + 36175872);
  u16* PBUF = (u16*)(ws + 38797312);
  u16* RB   = (u16*)(ws + 44040192);  // RB/KB/VB contiguous
  u16* KB   = (u16*)(ws + 60817408);
  u16* VB   = (u16*)(ws + 77594624);
  u16* YB   = (u16*)(ws + 94371840);
  float* DEC  = (float*)(ws + 8388608);
  u16* AO   = (u16*)(ws + 8388608);

  // ---- d_out scratch ----
  float* out       = (float*)d_out;
  float* shift_out = out + 8388608;
  float* wkv_out   = out + 8396800;
  float* vf_out    = out + 8921088;
  u16* XRKV = (u16*)d_out;                        // XR/XK/XV/XW: 64 MB, dead after fused GEMM
  u16* WINb = (u16*)d_out;
  u16* AINb = (u16*)((char*)d_out + 16777216);
  u16* VINb = (u16*)((char*)d_out + 35684352);

  // weight prep
  k_cast4<<<16384, 256, 0, stream>>>(Wr, Wk, Wv, Wo, (u16*)ws);
  k_tpadA<<<2560, 256, 0, stream>>>(w1, a1, v1, g1, w2, a2, v2, g2, (u16*)ws);

  // token-shift mix precompute: XR,XK,XV,XW (bf16, into d_out scratch)
  k_prep4<<<8192, 256, 0, stream>>>(x, shift_in, x_r, x_k, x_v, x_w,
                                    XRKV, XRKV + 8388608u, XRKV + 16777216u, XRKV + 25165824u);

  // fused r/k/v + stage-1 GEMM (single launch, 53x32)
  k_gemm<2><<<dim3(53,32), 256, 0, stream>>>(XRKV, x, shift_in, x_a, x_g,
                                             WRB, (float*)PBUF, RB, 2048, 2048, 2048, 2048);

  // fused stage-2 GEMMs (single launch, 64x32) — overwrites dead XR.. regions
  k_gemm<3><<<dim3(64,32), 256, 0, stream>>>(PBUF, nullptr, nullptr, nullptr, nullptr,
                                             B2W, nullptr, (u16*)d_out, 0, 640, 128, 2048);

  // elementwise post
  k_post1<<<32768, 256, 0, stream>>>(KB, VB, WINb, AINb, VINb, v_first,
                                     w0, a0, v0, k_k, k_a, DEC);

  // sequential WKV scan (v4)
  k_scan<<<1024, 64, 0, stream>>>(RB, DEC, KB, VB, VINb, AINb, wkv_in, YB, wkv_out);

  // groupnorm + bonus + gate
  k_post2<<<32768, 256, 0, stream>>>(YB, RB, KB, VB, (u16*)((char*)d_out + 52461568),
                                     r_k, ln_w, ln_b, AO);

  // final GEMM -> out
  k_gemm<0><<<dim3(16,32), 256, 0, stream>>>(AO, nullptr, nullptr, nullptr, nullptr,
                                             WOB, out, nullptr, 2048, 2048, 2048, 2048);

  // small outputs last
  k_shift<<<8, 256, 0, stream>>>(x, shift_out);
  hipMemcpyAsync(vf_out, v_first, 33554432, hipMemcpyDeviceToDevice, stream);
}

// Round 10
// 760.630 us; speedup vs baseline: 1.2973x; 1.0013x over previous
//
#include <hip/hip_runtime.h>
#include <hip/hip_bf16.h>
#include <stdint.h>

typedef unsigned short u16;
typedef unsigned int u32;
typedef __attribute__((ext_vector_type(8))) short short8;
typedef __attribute__((ext_vector_type(4))) float f32x4;

#define BB 4
#define TT 1024
#define CC 2048

// ---------- helpers ----------
__device__ __forceinline__ u16 f2bf(float f){
  __hip_bfloat16 h = __float2bfloat16(f);
  return *reinterpret_cast<u16*>(&h);
}
__device__ __forceinline__ float bf2f(u16 h){
  union { u32 u; float f; } v; v.u = ((u32)h) << 16; return v.f;
}

__device__ __forceinline__ void gload16(const void* g, void* s){
  __builtin_amdgcn_global_load_lds((const __attribute__((address_space(1))) u32*)g,
                                   (__attribute__((address_space(3))) u32*)s, 16, 0, 0);
}

__device__ __forceinline__ float wave_sum64(float x){
  #pragma unroll
  for (int m = 1; m < 64; m <<= 1) x += __shfl_xor(x, m, 64);
  return x;
}

template<int N>
__device__ __forceinline__ float ror_add(float x){
  int t = __builtin_amdgcn_update_dpp(0, __builtin_bit_cast(int, x), 0x120 | N, 0xF, 0xF, false);
  return x + __builtin_bit_cast(float, t);
}
__device__ __forceinline__ float red16(float x){
  x = ror_add<8>(x); x = ror_add<4>(x); x = ror_add<2>(x); x = ror_add<1>(x);
  return x;
}

// ---------- fused weight casts: Wr,Wk,Wv,Wo -> bf16 (one launch) ----------
__global__ __launch_bounds__(256) void k_cast4(
  const float* __restrict__ wr, const float* __restrict__ wk,
  const float* __restrict__ wv, const float* __restrict__ wo,
  u16* __restrict__ wsb)
{
  int i = blockIdx.x*256 + threadIdx.x;
  int seg = i >> 20;
  int off = (i & 1048575) * 4;
  const float* src = (seg==0) ? wr : (seg==1) ? wk : (seg==2) ? wv : wo;
  const size_t dofs = (seg==0) ? 4194304u : (seg==1) ? 8388608u : (seg==2) ? 12582912u : 0u;
  float4 v = *(const float4*)&src[off];
  *(ushort4*)&wsb[dofs + off] = make_ushort4(f2bf(v.x), f2bf(v.y), f2bf(v.z), f2bf(v.w));
}

// ---------- fused tiled transposes: 8 matrices, LDS 32x33 ----------
__global__ __launch_bounds__(256) void k_tpadA(
  const float* __restrict__ w1, const float* __restrict__ a1,
  const float* __restrict__ v1, const float* __restrict__ g1,
  const float* __restrict__ w2, const float* __restrict__ a2,
  const float* __restrict__ v2, const float* __restrict__ g2,
  u16* __restrict__ wsb)
{
  __shared__ float lds[32][33];
  const int blk = blockIdx.x;
  const float* src; int R, S, Rpad, tile, tiles_r; size_t dst;
  if      (blk <  256){ src=w1; R=2048; S=96;   Rpad=2048; dst=16777216u; tile=blk;      tiles_r=64; }
  else if (blk <  512){ src=a1; R=2048; S=96;   Rpad=2048; dst=17039360u; tile=blk-256;  tiles_r=64; }
  else if (blk <  768){ src=v1; R=2048; S=64;   Rpad=2048; dst=17301504u; tile=blk-512;  tiles_r=64; }
  else if (blk < 1280){ src=g1; R=2048; S=256;  Rpad=2048; dst=17563648u; tile=blk-768;  tiles_r=64; }
  else if (blk < 1536){ src=w2; R=96;   S=2048; Rpad=128;  dst=18087936u; tile=blk-1280; tiles_r=4;  }
  else if (blk < 1792){ src=a2; R=96;   S=2048; Rpad=128;  dst=18350080u; tile=blk-1536; tiles_r=4;  }
  else if (blk < 2048){ src=v2; R=64;   S=2048; Rpad=128;  dst=18612224u; tile=blk-1792; tiles_r=4;  }
  else                { src=g2; R=256;  S=2048; Rpad=256;  dst=18874368u; tile=blk-2048; tiles_r=8;  }
  const int tr = tile % tiles_r, ts = tile / tiles_r;
  const int r0 = tr*32, s0 = ts*32;
  const int tj = threadIdx.x & 31, ti = threadIdx.x >> 5;
  #pragma unroll
  for (int p=0;p<4;p++){
    int rr = r0 + p*8 + ti, ss = s0 + tj;
    lds[p*8+ti][tj] = (rr < R && ss < S) ? src[(size_t)rr*S + ss] : 0.f;
  }
  __syncthreads();
  #pragma unroll
  for (int p=0;p<4;p++){
    int sl = p*8 + ti, rl = tj;
    wsb[dst + (size_t)(s0+sl)*Rpad + r0 + rl] = f2bf(lds[rl][sl]);
  }
}

// ---------- prep: token-shift mix -> XR,XK,XV,XW bf16 (one pass over x) ----------
__global__ __launch_bounds__(256) void k_prep4(
  const float* __restrict__ x, const float* __restrict__ shift_in,
  const float* __restrict__ mr, const float* __restrict__ mk,
  const float* __restrict__ mv, const float* __restrict__ mw,
  u16* __restrict__ xr, u16* __restrict__ xk, u16* __restrict__ xv, u16* __restrict__ xw)
{
  int idx = blockIdx.x*256 + threadIdx.x;
  int c4 = (idx & 511) * 4;
  int t  = (idx >> 9) & (TT-1);
  int b  = idx >> 19;
  size_t xo = ((size_t)(b*TT + t))*CC + c4;
  float4 xc = *(const float4*)&x[xo];
  float4 xp = (t == 0) ? *(const float4*)&shift_in[(size_t)b*CC + c4]
                       : *(const float4*)&x[xo - CC];
  float d0 = xp.x-xc.x, d1 = xp.y-xc.y, d2 = xp.z-xc.z, d3 = xp.w-xc.w;
#define MIXO(mp, op) { float4 m = *(const float4*)&mp[c4]; \
    *(ushort4*)&op[xo] = make_ushort4(f2bf(fmaf(d0,m.x,xc.x)), f2bf(fmaf(d1,m.y,xc.y)), \
                                      f2bf(fmaf(d2,m.z,xc.z)), f2bf(fmaf(d3,m.w,xc.w))); }
  MIXO(mr, xr); MIXO(mk, xk); MIXO(mv, xv); MIXO(mw, xw);
#undef MIXO
}

// ---------- GEMM: C[M,N] = A[M,K](bf16) * Bt[N,K]^T(bf16) ----------
template<int AMODE>
__global__ __launch_bounds__(256) void k_gemm(
  const u16* __restrict__ Abf,
  const float* __restrict__ xg, const float* __restrict__ shiftg,
  const float* __restrict__ ma, const float* __restrict__ mg,
  const u16* __restrict__ Bt, float* __restrict__ Cf, u16* __restrict__ Cb,
  int K, int lda, int ldb, int ldc)
{
  __shared__ alignas(16) u16 sA[128*32];
  __shared__ alignas(16) u16 sB[128*32];
  const int tid = threadIdx.x;
  const int wv = tid >> 6, ln = tid & 63;
  const int bx = blockIdx.x;
  const int row0 = blockIdx.y * 128;
  const int wr = wv >> 1, wc = wv & 1;

  const float* mixv = nullptr;
  const u16* Ap = Abf;
  const u16* Btp = Bt;
  u16* Cbp = Cb;
  bool bmix = false;
  int bcol0 = bx * 128;
  int ccol0 = bx * 128;
  int ldaa = lda, ldbb = ldb, ldcc = ldc;
  int KK = K, act = 0;

  if (AMODE == 2){
    if (bx < 48){
      int sel = bx >> 4;
      Ap = Abf + (size_t)sel * 8388608u;
      Cbp = Cb + (size_t)sel * 8388608u;
      ccol0 = (bx & 15) * 128;
      ldcc = 2048; ldaa = 2048;
    } else {
      int sb = bx - 48;
      Cbp = (u16*)Cf;
      ccol0 = sb * 128;
      ldcc = 640;
      act = (sb==0) ? 1 : (sb>=3 ? 2 : 0);
      if (sb == 0){ Ap = Abf + 25165824u; ldaa = 2048; }
      else if (sb == 2){ Ap = Abf + 16777216u; ldaa = 2048; }
      else { bmix = true; mixv = (sb==1) ? ma : mg; }
    }
  }
  if (AMODE == 3){
    int sel = bx >> 4;
    Ap = Abf + sel*128;
    Btp = Bt + (size_t)sel * 262144u;
    ldbb = (sel==3) ? 256 : 128;
    KK = (sel==3) ? 256 : 128;
    const int coffs[4] = {0, 8388608, 17842176, 26230784};
    Cbp = Cb + coffs[sel];
    ccol0 = (bx & 15) * 128;
    bcol0 = ccol0;
    ldcc = 2048;
  }

  f32x4 acc[4][4] = {};
  const int ob0 = wv*2048;
  const int o0  = ob0 + ln*16;
  const int rA0 = o0 >> 6;
  const int ke0 = (o0 & 63) >> 1;
  const int ar  = tid >> 2;
  const int akc = (tid & 3) * 8;

  for (int k0 = 0; k0 < KK; k0 += 32){
    __syncthreads();
    if (AMODE != 2 || !bmix){
      gload16(&Ap[(size_t)(row0 + rA0     )*ldaa + k0 + ke0], (void*)((char*)sA + ob0));
      gload16(&Ap[(size_t)(row0 + rA0 + 16)*ldaa + k0 + ke0], (void*)((char*)sA + ob0 + 1024));
    }
    gload16(&Btp[(size_t)(bcol0 + rA0     )*ldbb + k0 + ke0], (void*)((char*)sB + ob0));
    gload16(&Btp[(size_t)(bcol0 + rA0 + 16)*ldbb + k0 + ke0], (void*)((char*)sB + ob0 + 1024));
    if (AMODE == 2 && bmix){
      float4 m0 = *(const float4*)&mixv[k0 + akc];
      float4 m1 = *(const float4*)&mixv[k0 + akc + 4];
      #pragma unroll
      for (int it = 0; it < 2; ++it){
        int r = ar + it*64;
        int gr = row0 + r;
        size_t xo = (size_t)gr*CC + k0 + akc;
        float4 c0 = *(const float4*)&xg[xo];
        float4 c1 = *(const float4*)&xg[xo + 4];
        const float* pp = ((gr & (TT-1)) == 0) ? &shiftg[(size_t)(gr >> 10)*CC + k0 + akc]
                                               : &xg[xo - CC];
        float4 p0 = *(const float4*)&pp[0];
        float4 p1 = *(const float4*)&pp[4];
        short8 vvv;
        vvv[0] = (short)f2bf(c0.x + (p0.x - c0.x)*m0.x);
        vvv[1] = (short)f2bf(c0.y + (p0.y - c0.y)*m0.y);
        vvv[2] = (short)f2bf(c0.z + (p0.z - c0.z)*m0.z);
        vvv[3] = (short)f2bf(c0.w + (p0.w - c0.w)*m0.w);
        vvv[4] = (short)f2bf(c1.x + (p1.x - c1.x)*m1.x);
        vvv[5] = (short)f2bf(c1.y + (p1.y - c1.y)*m1.y);
        vvv[6] = (short)f2bf(c1.z + (p1.z - c1.z)*m1.z);
        vvv[7] = (short)f2bf(c1.w + (p1.w - c1.w)*m1.w);
        *(short8*)&sA[r*32 + akc] = vvv;
      }
    }
    __syncthreads();
    short8 aF[4], bF[4];
    #pragma unroll
    for (int m=0;m<4;m++) aF[m] = *(const short8*)&sA[(wr*64 + m*16 + (ln&15))*32 + (ln>>4)*8];
    #pragma unroll
    for (int n=0;n<4;n++) bF[n] = *(const short8*)&sB[(wc*64 + n*16 + (ln&15))*32 + (ln>>4)*8];
    #pragma unroll
    for (int m=0;m<4;m++)
      #pragma unroll
      for (int n=0;n<4;n++)
        acc[m][n] = __builtin_amdgcn_mfma_f32_16x16x32_bf16(aF[m], bF[n], acc[m][n], 0,0,0);
  }

  const int cr = (ln >> 4) * 4, ccol = ln & 15;
  #pragma unroll
  for (int m=0;m<4;m++){
    #pragma unroll
    for (int n=0;n<4;n++){
      int gc = ccol0 + wc*64 + n*16 + ccol;
      #pragma unroll
      for (int j=0;j<4;j++){
        int gr = row0 + wr*64 + m*16 + cr + j;
        float v = acc[m][n][j];
        if (AMODE == 0){
          Cf[(size_t)gr*ldcc + gc] = v;
        } else {
          if (act == 1) v = tanhf(v);
          else if (act == 2) v = 1.f/(1.f + expf(-v));
          Cbp[(size_t)gr*ldcc + gc] = f2bf(v);
        }
      }
    }
  }
}

// ---------- post1 ----------
__global__ __launch_bounds__(256) void k_post1(
  u16* __restrict__ kb, u16* __restrict__ vb, const u16* __restrict__ winb,
  u16* __restrict__ ainb, u16* __restrict__ vinb,
  const float* __restrict__ vfirst,
  const float* __restrict__ w0, const float* __restrict__ a0, const float* __restrict__ v0,
  const float* __restrict__ kkv, const float* __restrict__ kav,
  float* __restrict__ dec)
{
  int grp = blockIdx.x*4 + (threadIdx.x >> 6);
  int n = threadIdx.x & 63;
  int i = grp >> 5, h = grp & 31;
  int c = h*64 + n;
  size_t idx = (size_t)i*CC + c;
  float k  = bf2f(kb[idx]),  v = bf2f(vb[idx]);
  float wi = bf2f(winb[idx]), ai = bf2f(ainb[idx]), vi = bf2f(vinb[idx]);
  float vf = vfirst[idx];
  float a  = 1.f/(1.f + expf(-(a0[c] + ai)));
  float z  = -(w0[c] + wi);
  float sp = (z > 15.f) ? z : log1pf(expf(z));
  float decay = expf(-expf(-sp - 0.5f));
  float vg = 1.f/(1.f + expf(-(v0[c] + vi)));
  float vfin = v + (vf - v)*vg;
  float kkr = k * kkv[c];
  float ss = wave_sum64(kkr*kkr);
  float kkn = kkr / fmaxf(sqrtf(ss), 1e-12f);
  float kfin = k * (1.f + (a - 1.f)*kav[c]);
  kb[idx] = f2bf(kfin);
  vb[idx] = f2bf(vfin);
  dec[idx] = decay;
  vinb[idx] = f2bf(kkn);
  ainb[idx] = f2bf(-(kkn * a));
}

// ---------- WKV scan v4 + full-register budget (1 wave/EU => up to 512 VGPR) ----------
#define DECL_CHUNK(S) float4 w##S[4]; ushort4 b##S[4], k##S[4], kk##S[4], r##S[4]; u32 v##S[4];

#define SCAN_ISSUE(S, t0) do {                                                   \
  _Pragma("unroll")                                                              \
  for (int s_=0; s_<4; ++s_){                                                    \
    size_t o_ = gc0 + (size_t)((t0)+s_)*CC;                                      \
    w##S[s_]  = *(const float4*)&wb[o_];                                         \
    b##S[s_]  = *(const ushort4*)&bbp[o_];                                       \
    k##S[s_]  = *(const ushort4*)&kb[o_];                                        \
    kk##S[s_] = *(const ushort4*)&kkb[o_];                                       \
    r##S[s_]  = *(const ushort4*)&rb[o_];                                        \
    v##S[s_]  = *(const u32*)&vb[gv0 + (size_t)((t0)+s_)*CC];                    \
  }                                                                              \
} while(0)

#define SCAN_CHUNK(S, t0) do {                                                   \
  _Pragma("unroll")                                                              \
  for (int s_=0; s_<4; ++s_){                                                    \
    const float w_0=w##S[s_].x, w_1=w##S[s_].y, w_2=w##S[s_].z, w_3=w##S[s_].w;  \
    const float b_0=bf2f(b##S[s_].x), b_1=bf2f(b##S[s_].y),                      \
                b_2=bf2f(b##S[s_].z), b_3=bf2f(b##S[s_].w);                      \
    const float k_0=bf2f(k##S[s_].x), k_1=bf2f(k##S[s_].y),                      \
                k_2=bf2f(k##S[s_].z), k_3=bf2f(k##S[s_].w);                      \
    const float q_0=bf2f(kk##S[s_].x), q_1=bf2f(kk##S[s_].y),                    \
                q_2=bf2f(kk##S[s_].z), q_3=bf2f(kk##S[s_].w);                    \
    const float r_0=bf2f(r##S[s_].x), r_1=bf2f(r##S[s_].y),                      \
                r_2=bf2f(r##S[s_].z), r_3=bf2f(r##S[s_].w);                      \
    const u32 vpk_ = v##S[s_];                                                   \
    const float vv0_ = bf2f((u16)(vpk_ & 0xFFFFu));                              \
    const float vv1_ = bf2f((u16)(vpk_ >> 16));                                  \
    float p0_ = fmaf(st[0][0],q_0, st[0][1]*q_1) + fmaf(st[0][2],q_2, st[0][3]*q_3); \
    float p1_ = fmaf(st[1][0],q_0, st[1][1]*q_1) + fmaf(st[1][2],q_2, st[1][3]*q_3); \
    p0_ = red16(p0_); p1_ = red16(p1_);                                          \
    st[0][0] = fmaf(st[0][0],w_0, fmaf(p0_,b_0, vv0_*k_0));                      \
    st[0][1] = fmaf(st[0][1],w_1, fmaf(p0_,b_1, vv0_*k_1));                      \
    st[0][2] = fmaf(st[0][2],w_2, fmaf(p0_,b_2, vv0_*k_2));                      \
    st[0][3] = fmaf(st[0][3],w_3, fmaf(p0_,b_3, vv0_*k_3));                      \
    st[1][0] = fmaf(st[1][0],w_0, fmaf(p1_,b_0, vv1_*k_0));                      \
    st[1][1] = fmaf(st[1][1],w_1, fmaf(p1_,b_1, vv1_*k_1));                      \
    st[1][2] = fmaf(st[1][2],w_2, fmaf(p1_,b_2, vv1_*k_2));                      \
    st[1][3] = fmaf(st[1][3],w_3, fmaf(p1_,b_3, vv1_*k_3));                      \
    float y0_ = fmaf(st[0][0],r_0, st[0][1]*r_1) + fmaf(st[0][2],r_2, st[0][3]*r_3); \
    float y1_ = fmaf(st[1][0],r_0, st[1][1]*r_1) + fmaf(st[1][2],r_2, st[1][3]*r_3); \
    y0_ = red16(y0_); y1_ = red16(y1_);                                          \
    if (cg == 0){                                                                \
      u32 pk_ = (u32)f2bf(y0_) | ((u32)f2bf(y1_) << 16);                         \
      *(u32*)&yb[gv0 + (size_t)((t0)+s_)*CC] = pk_;                              \
    }                                                                            \
  }                                                                              \
} while(0)

__global__ __launch_bounds__(64, 1) void k_scan(
  const u16* __restrict__ rb, const float* __restrict__ wb,
  const u16* __restrict__ kb, const u16* __restrict__ vb,
  const u16* __restrict__ kkb, const u16* __restrict__ bbp,
  const float* __restrict__ wkv_in, u16* __restrict__ yb, float* __restrict__ wkv_out)
{
  const int blk = blockIdx.x;
  const int bh = blk & 127, oct = blk >> 7;
  const int b = bh >> 5, h = bh & 31;
  const int ln = threadIdx.x;
  const int rg = ln >> 4;
  const int cg = ln & 15;
  const int row0 = oct*8 + rg*2;
  const int col0 = cg*4;

  float st[2][4];
  {
    const float* sp0 = &wkv_in[((size_t)bh*64 + row0    )*64 + col0];
    const float* sp1 = &wkv_in[((size_t)bh*64 + row0 + 1)*64 + col0];
    float4 a = *(const float4*)sp0, c = *(const float4*)sp1;
    st[0][0]=a.x; st[0][1]=a.y; st[0][2]=a.z; st[0][3]=a.w;
    st[1][0]=c.x; st[1][1]=c.y; st[1][2]=c.z; st[1][3]=c.w;
  }

  const size_t gc0 = ((size_t)b*TT)*CC + h*64 + col0;
  const size_t gv0 = ((size_t)b*TT)*CC + h*64 + row0;

  DECL_CHUNK(A) DECL_CHUNK(B) DECL_CHUNK(C) DECL_CHUNK(D)

  SCAN_ISSUE(A, 0);
  SCAN_ISSUE(B, 4);
  SCAN_ISSUE(C, 8);
  for (int it = 0; it < 64; ++it){
    const int t0 = it*16;
    if (t0+12 < TT) SCAN_ISSUE(D, t0+12);
    SCAN_CHUNK(A, t0);
    if (t0+16 < TT) SCAN_ISSUE(A, t0+16);
    SCAN_CHUNK(B, t0+4);
    if (t0+20 < TT) SCAN_ISSUE(B, t0+20);
    SCAN_CHUNK(C, t0+8);
    if (t0+24 < TT) SCAN_ISSUE(C, t0+24);
    SCAN_CHUNK(D, t0+12);
  }

  {
    float* wo0 = &wkv_out[((size_t)bh*64 + row0    )*64 + col0];
    float* wo1 = &wkv_out[((size_t)bh*64 + row0 + 1)*64 + col0];
    *(float4*)wo0 = make_float4(st[0][0], st[0][1], st[0][2], st[0][3]);
    *(float4*)wo1 = make_float4(st[1][0], st[1][1], st[1][2], st[1][3]);
  }
}

// ---------- post2 ----------
__global__ __launch_bounds__(256) void k_post2(
  const u16* __restrict__ ybuf, const u16* __restrict__ rbuf,
  const u16* __restrict__ kfb, const u16* __restrict__ vfb,
  const u16* __restrict__ gbuf, const float* __restrict__ rk,
  const float* __restrict__ lnw, const float* __restrict__ lnb, u16* __restrict__ ao)
{
  int grp = blockIdx.x*4 + (threadIdx.x >> 6);
  int n = threadIdx.x & 63;
  int i = grp >> 5, h = grp & 31;
  int c = h*64 + n;
  size_t idx = (size_t)i*CC + c;
  float y = bf2f(ybuf[idx]);
  float s1 = wave_sum64(y);
  float s2 = wave_sum64(y*y);
  float mu = s1 * (1.f/64.f);
  float var = s2 * (1.f/64.f) - mu*mu;
  float yn = (y - mu) * rsqrtf(var + 6.4e-4f) * lnw[c] + lnb[c];
  float rv = bf2f(rbuf[idx]), kv = bf2f(kfb[idx]);
  float s3 = wave_sum64(rv * kv * rk[c]);
  float bonus = s3 * bf2f(vfb[idx]);
  ao[idx] = f2bf((yn + bonus) * bf2f(gbuf[idx]));
}

// ---------- shift_state_out = x[:, -1] ----------
__global__ __launch_bounds__(256) void k_shift(const float* __restrict__ x, float* __restrict__ so){
  int i = blockIdx.x*256 + threadIdx.x;
  int b = i >> 9, c4 = (i & 511)*4;
  *(float4*)&so[(size_t)b*CC + c4] = *(const float4*)&x[((size_t)(b*TT + TT-1))*CC + c4];
}

// ---------- launch ----------
extern "C" void kernel_launch(void* const* d_in, const int* in_sizes, int n_in,
                              void* d_out, int out_size, void* d_ws, size_t ws_size,
                              hipStream_t stream)
{
  const float* x        = (const float*)d_in[0];
  const float* shift_in = (const float*)d_in[1];
  const float* wkv_in   = (const float*)d_in[2];
  const float* v_first  = (const float*)d_in[3];
  const float* x_r = (const float*)d_in[4];
  const float* x_w = (const float*)d_in[5];
  const float* x_k = (const float*)d_in[6];
  const float* x_v = (const float*)d_in[7];
  const float* x_a = (const float*)d_in[8];
  const float* x_g = (const float*)d_in[9];
  const float* w0 = (const float*)d_in[10];
  const float* w1 = (const float*)d_in[11];
  const float* w2 = (const float*)d_in[12];
  const float* a0 = (const float*)d_in[13];
  const float* a1 = (const float*)d_in[14];
  const float* a2 = (const float*)d_in[15];
  const float* v0 = (const float*)d_in[16];
  const float* v1 = (const float*)d_in[17];
  const float* v2 = (const float*)d_in[18];
  const float* g1 = (const float*)d_in[19];
  const float* g2 = (const float*)d_in[20];
  const float* k_k = (const float*)d_in[21];
  const float* k_a = (const float*)d_in[22];
  const float* r_k = (const float*)d_in[23];
  const float* Wr = (const float*)d_in[24];
  const float* Wk = (const float*)d_in[25];
  const float* Wv = (const float*)d_in[26];
  const float* Wo = (const float*)d_in[27];
  const float* ln_w = (const float*)d_in[28];
  const float* ln_b = (const float*)d_in[29];

  // ---- ws layout ----
  char* ws = (char*)d_ws;
  u16* WOB  = (u16*)(ws + 0);
  u16* WRB  = (u16*)(ws + 8388608);
  u16* B2W  = (u16*)(ws + 36175872);
  u16* PBUF = (u16*)(ws + 38797312);
  u16* RB   = (u16*)(ws + 44040192);
  u16* KB   = (u16*)(ws + 60817408);
  u16* VB   = (u16*)(ws + 77594624);
  u16* YB   = (u16*)(ws + 94371840);
  float* DEC  = (float*)(ws + 8388608);
  u16* AO   = (u16*)(ws + 8388608);

  // ---- d_out scratch ----
  float* out       = (float*)d_out;
  float* shift_out = out + 8388608;
  float* wkv_out   = out + 8396800;
  float* vf_out    = out + 8921088;
  u16* XRKV = (u16*)d_out;
  u16* WINb = (u16*)d_out;
  u16* AINb = (u16*)((char*)d_out + 16777216);
  u16* VINb = (u16*)((char*)d_out + 35684352);

  // weight prep
  k_cast4<<<16384, 256, 0, stream>>>(Wr, Wk, Wv, Wo, (u16*)ws);
  k_tpadA<<<2560, 256, 0, stream>>>(w1, a1, v1, g1, w2, a2, v2, g2, (u16*)ws);

  // token-shift mix precompute
  k_prep4<<<8192, 256, 0, stream>>>(x, shift_in, x_r, x_k, x_v, x_w,
                                    XRKV, XRKV + 8388608u, XRKV + 16777216u, XRKV + 25165824u);

  // fused r/k/v + stage-1 GEMM
  k_gemm<2><<<dim3(53,32), 256, 0, stream>>>(XRKV, x, shift_in, x_a, x_g,
                                             WRB, (float*)PBUF, RB, 2048, 2048, 2048, 2048);

  // fused stage-2 GEMMs
  k_gemm<3><<<dim3(64,32), 256, 0, stream>>>(PBUF, nullptr, nullptr, nullptr, nullptr,
                                             B2W, nullptr, (u16*)d_out, 0, 640, 128, 2048);

  // elementwise post
  k_post1<<<32768, 256, 0, stream>>>(KB, VB, WINb, AINb, VINb, v_first,
                                     w0, a0, v0, k_k, k_a, DEC);

  // sequential WKV scan
  k_scan<<<1024, 64, 0, stream>>>(RB, DEC, KB, VB, VINb, AINb, wkv_in, YB, wkv_out);

  // groupnorm + bonus + gate
  k_post2<<<32768, 256, 0, stream>>>(YB, RB, KB, VB, (u16*)((char*)d_out + 52461568),
                                     r_k, ln_w, ln_b, AO);

  // final GEMM -> out
  k_gemm<0><<<dim3(16,32), 256, 0, stream>>>(AO, nullptr, nullptr, nullptr, nullptr,
                                             WOB, out, nullptr, 2048, 2048, 2048, 2048);

  // small outputs last
  k_shift<<<8, 256, 0, stream>>>(x, shift_out);
  hipMemcpyAsync(vf_out, v_first, 33554432, hipMemcpyDeviceToDevice, stream);
}

// Round 11
// 733.893 us; speedup vs baseline: 1.3445x; 1.0364x over previous
//
#include <hip/hip_runtime.h>
#include <hip/hip_bf16.h>
#include <stdint.h>

typedef unsigned short u16;
typedef unsigned int u32;
typedef unsigned long long u64;
typedef __attribute__((ext_vector_type(8))) short short8;
typedef __attribute__((ext_vector_type(4))) float f32x4;
typedef __attribute__((ext_vector_type(2))) unsigned int u32x2;

#define BB 4
#define TT 1024
#define CC 2048

// ---------- helpers ----------
__device__ __forceinline__ u16 f2bf(float f){
  __hip_bfloat16 h = __float2bfloat16(f);
  return *reinterpret_cast<u16*>(&h);
}
__device__ __forceinline__ float bf2f(u16 h){
  union { u32 u; float f; } v; v.u = ((u32)h) << 16; return v.f;
}
__device__ __forceinline__ float bflo(u32 p){
  union { u32 u; float f; } v; v.u = p << 16; return v.f;
}
__device__ __forceinline__ float bfhi(u32 p){
  union { u32 u; float f; } v; v.u = p & 0xFFFF0000u; return v.f;
}

__device__ __forceinline__ void gload16(const void* g, void* s){
  __builtin_amdgcn_global_load_lds((const __attribute__((address_space(1))) u32*)g,
                                   (__attribute__((address_space(3))) u32*)s, 16, 0, 0);
}

__device__ __forceinline__ float wave_sum64(float x){
  #pragma unroll
  for (int m = 1; m < 64; m <<= 1) x += __shfl_xor(x, m, 64);
  return x;
}

template<int N>
__device__ __forceinline__ float ror_add(float x){
  int t = __builtin_amdgcn_update_dpp(0, __builtin_bit_cast(int, x), 0x120 | N, 0xF, 0xF, false);
  return x + __builtin_bit_cast(float, t);
}
__device__ __forceinline__ float red16(float x){
  x = ror_add<8>(x); x = ror_add<4>(x); x = ror_add<2>(x); x = ror_add<1>(x);
  return x;
}

// ---------- fused weight casts ----------
__global__ __launch_bounds__(256) void k_cast4(
  const float* __restrict__ wr, const float* __restrict__ wk,
  const float* __restrict__ wv, const float* __restrict__ wo,
  u16* __restrict__ wsb)
{
  int i = blockIdx.x*256 + threadIdx.x;
  int seg = i >> 20;
  int off = (i & 1048575) * 4;
  const float* src = (seg==0) ? wr : (seg==1) ? wk : (seg==2) ? wv : wo;
  const size_t dofs = (seg==0) ? 4194304u : (seg==1) ? 8388608u : (seg==2) ? 12582912u : 0u;
  float4 v = *(const float4*)&src[off];
  *(ushort4*)&wsb[dofs + off] = make_ushort4(f2bf(v.x), f2bf(v.y), f2bf(v.z), f2bf(v.w));
}

// ---------- fused tiled transposes ----------
__global__ __launch_bounds__(256) void k_tpadA(
  const float* __restrict__ w1, const float* __restrict__ a1,
  const float* __restrict__ v1, const float* __restrict__ g1,
  const float* __restrict__ w2, const float* __restrict__ a2,
  const float* __restrict__ v2, const float* __restrict__ g2,
  u16* __restrict__ wsb)
{
  __shared__ float lds[32][33];
  const int blk = blockIdx.x;
  const float* src; int R, S, Rpad, tile, tiles_r; size_t dst;
  if      (blk <  256){ src=w1; R=2048; S=96;   Rpad=2048; dst=16777216u; tile=blk;      tiles_r=64; }
  else if (blk <  512){ src=a1; R=2048; S=96;   Rpad=2048; dst=17039360u; tile=blk-256;  tiles_r=64; }
  else if (blk <  768){ src=v1; R=2048; S=64;   Rpad=2048; dst=17301504u; tile=blk-512;  tiles_r=64; }
  else if (blk < 1280){ src=g1; R=2048; S=256;  Rpad=2048; dst=17563648u; tile=blk-768;  tiles_r=64; }
  else if (blk < 1536){ src=w2; R=96;   S=2048; Rpad=128;  dst=18087936u; tile=blk-1280; tiles_r=4;  }
  else if (blk < 1792){ src=a2; R=96;   S=2048; Rpad=128;  dst=18350080u; tile=blk-1536; tiles_r=4;  }
  else if (blk < 2048){ src=v2; R=64;   S=2048; Rpad=128;  dst=18612224u; tile=blk-1792; tiles_r=4;  }
  else                { src=g2; R=256;  S=2048; Rpad=256;  dst=18874368u; tile=blk-2048; tiles_r=8;  }
  const int tr = tile % tiles_r, ts = tile / tiles_r;
  const int r0 = tr*32, s0 = ts*32;
  const int tj = threadIdx.x & 31, ti = threadIdx.x >> 5;
  #pragma unroll
  for (int p=0;p<4;p++){
    int rr = r0 + p*8 + ti, ss = s0 + tj;
    lds[p*8+ti][tj] = (rr < R && ss < S) ? src[(size_t)rr*S + ss] : 0.f;
  }
  __syncthreads();
  #pragma unroll
  for (int p=0;p<4;p++){
    int sl = p*8 + ti, rl = tj;
    wsb[dst + (size_t)(s0+sl)*Rpad + r0 + rl] = f2bf(lds[rl][sl]);
  }
}

// ---------- prep: token-shift mix -> XR,XK,XV,XW bf16 ----------
__global__ __launch_bounds__(256) void k_prep4(
  const float* __restrict__ x, const float* __restrict__ shift_in,
  const float* __restrict__ mr, const float* __restrict__ mk,
  const float* __restrict__ mv, const float* __restrict__ mw,
  u16* __restrict__ xr, u16* __restrict__ xk, u16* __restrict__ xv, u16* __restrict__ xw)
{
  int idx = blockIdx.x*256 + threadIdx.x;
  int c4 = (idx & 511) * 4;
  int t  = (idx >> 9) & (TT-1);
  int b  = idx >> 19;
  size_t xo = ((size_t)(b*TT + t))*CC + c4;
  float4 xc = *(const float4*)&x[xo];
  float4 xp = (t == 0) ? *(const float4*)&shift_in[(size_t)b*CC + c4]
                       : *(const float4*)&x[xo - CC];
  float d0 = xp.x-xc.x, d1 = xp.y-xc.y, d2 = xp.z-xc.z, d3 = xp.w-xc.w;
#define MIXO(mp, op) { float4 m = *(const float4*)&mp[c4]; \
    *(ushort4*)&op[xo] = make_ushort4(f2bf(fmaf(d0,m.x,xc.x)), f2bf(fmaf(d1,m.y,xc.y)), \
                                      f2bf(fmaf(d2,m.z,xc.z)), f2bf(fmaf(d3,m.w,xc.w))); }
  MIXO(mr, xr); MIXO(mk, xk); MIXO(mv, xv); MIXO(mw, xw);
#undef MIXO
}

// ---------- GEMM body (device) ----------
template<int AMODE>
__device__ __forceinline__ void gemm_body(
  const u16* __restrict__ Abf,
  const float* __restrict__ xg, const float* __restrict__ shiftg,
  const float* __restrict__ ma, const float* __restrict__ mg,
  const u16* __restrict__ Bt, float* __restrict__ Cf, u16* __restrict__ Cb,
  int K, int lda, int ldb, int ldc)
{
  __shared__ alignas(16) u16 sA[128*32];
  __shared__ alignas(16) u16 sB[128*32];
  const int tid = threadIdx.x;
  const int wv = tid >> 6, ln = tid & 63;
  const int bx = blockIdx.x;
  const int row0 = blockIdx.y * 128;
  const int wr = wv >> 1, wc = wv & 1;

  const float* mixv = nullptr;
  const u16* Ap = Abf;
  const u16* Btp = Bt;
  u16* Cbp = Cb;
  bool bmix = false;
  int bcol0 = bx * 128;
  int ccol0 = bx * 128;
  int ldaa = lda, ldbb = ldb, ldcc = ldc;
  int KK = K, act = 0;

  if (AMODE == 2){
    if (bx < 48){
      int sel = bx >> 4;
      Ap = Abf + (size_t)sel * 8388608u;
      Cbp = Cb + (size_t)sel * 8388608u;
      ccol0 = (bx & 15) * 128;
      ldcc = 2048; ldaa = 2048;
    } else {
      int sb = bx - 48;
      Cbp = (u16*)Cf;
      ccol0 = sb * 128;
      ldcc = 640;
      act = (sb==0) ? 1 : (sb>=3 ? 2 : 0);
      if (sb == 0){ Ap = Abf + 25165824u; ldaa = 2048; }
      else if (sb == 2){ Ap = Abf + 16777216u; ldaa = 2048; }
      else { bmix = true; mixv = (sb==1) ? ma : mg; }
    }
  }
  if (AMODE == 3){
    int sel = bx >> 4;
    Ap = Abf + sel*128;
    Btp = Bt + (size_t)sel * 262144u;
    ldbb = (sel==3) ? 256 : 128;
    KK = (sel==3) ? 256 : 128;
    const int coffs[4] = {0, 8388608, 17842176, 26230784};
    Cbp = Cb + coffs[sel];
    ccol0 = (bx & 15) * 128;
    bcol0 = ccol0;
    ldcc = 2048;
  }

  f32x4 acc[4][4] = {};
  const int ob0 = wv*2048;
  const int o0  = ob0 + ln*16;
  const int rA0 = o0 >> 6;
  const int ke0 = (o0 & 63) >> 1;
  const int ar  = tid >> 2;
  const int akc = (tid & 3) * 8;

  for (int k0 = 0; k0 < KK; k0 += 32){
    __syncthreads();
    if (AMODE != 2 || !bmix){
      gload16(&Ap[(size_t)(row0 + rA0     )*ldaa + k0 + ke0], (void*)((char*)sA + ob0));
      gload16(&Ap[(size_t)(row0 + rA0 + 16)*ldaa + k0 + ke0], (void*)((char*)sA + ob0 + 1024));
    }
    gload16(&Btp[(size_t)(bcol0 + rA0     )*ldbb + k0 + ke0], (void*)((char*)sB + ob0));
    gload16(&Btp[(size_t)(bcol0 + rA0 + 16)*ldbb + k0 + ke0], (void*)((char*)sB + ob0 + 1024));
    if (AMODE == 2 && bmix){
      float4 m0 = *(const float4*)&mixv[k0 + akc];
      float4 m1 = *(const float4*)&mixv[k0 + akc + 4];
      #pragma unroll
      for (int it = 0; it < 2; ++it){
        int r = ar + it*64;
        int gr = row0 + r;
        size_t xo = (size_t)gr*CC + k0 + akc;
        float4 c0 = *(const float4*)&xg[xo];
        float4 c1 = *(const float4*)&xg[xo + 4];
        const float* pp = ((gr & (TT-1)) == 0) ? &shiftg[(size_t)(gr >> 10)*CC + k0 + akc]
                                               : &xg[xo - CC];
        float4 p0 = *(const float4*)&pp[0];
        float4 p1 = *(const float4*)&pp[4];
        short8 vvv;
        vvv[0] = (short)f2bf(c0.x + (p0.x - c0.x)*m0.x);
        vvv[1] = (short)f2bf(c0.y + (p0.y - c0.y)*m0.y);
        vvv[2] = (short)f2bf(c0.z + (p0.z - c0.z)*m0.z);
        vvv[3] = (short)f2bf(c0.w + (p0.w - c0.w)*m0.w);
        vvv[4] = (short)f2bf(c1.x + (p1.x - c1.x)*m1.x);
        vvv[5] = (short)f2bf(c1.y + (p1.y - c1.y)*m1.y);
        vvv[6] = (short)f2bf(c1.z + (p1.z - c1.z)*m1.z);
        vvv[7] = (short)f2bf(c1.w + (p1.w - c1.w)*m1.w);
        *(short8*)&sA[r*32 + akc] = vvv;
      }
    }
    __syncthreads();
    short8 aF[4], bF[4];
    #pragma unroll
    for (int m=0;m<4;m++) aF[m] = *(const short8*)&sA[(wr*64 + m*16 + (ln&15))*32 + (ln>>4)*8];
    #pragma unroll
    for (int n=0;n<4;n++) bF[n] = *(const short8*)&sB[(wc*64 + n*16 + (ln&15))*32 + (ln>>4)*8];
    #pragma unroll
    for (int m=0;m<4;m++)
      #pragma unroll
      for (int n=0;n<4;n++)
        acc[m][n] = __builtin_amdgcn_mfma_f32_16x16x32_bf16(aF[m], bF[n], acc[m][n], 0,0,0);
  }

  const int cr = (ln >> 4) * 4, ccol = ln & 15;
  #pragma unroll
  for (int m=0;m<4;m++){
    #pragma unroll
    for (int n=0;n<4;n++){
      int gc = ccol0 + wc*64 + n*16 + ccol;
      #pragma unroll
      for (int j=0;j<4;j++){
        int gr = row0 + wr*64 + m*16 + cr + j;
        float v = acc[m][n][j];
        if (AMODE == 0){
          Cf[(size_t)gr*ldcc + gc] = v;
        } else {
          if (act == 1) v = tanhf(v);
          else if (act == 2) v = 1.f/(1.f + expf(-v));
          Cbp[(size_t)gr*ldcc + gc] = f2bf(v);
        }
      }
    }
  }
}

// named wrappers (distinct rocprof identities)
__global__ __launch_bounds__(256) void k_gemm_rkv(
  const u16* Abf, const float* xg, const float* shiftg, const float* ma, const float* mg,
  const u16* Bt, float* Cf, u16* Cb, int K, int lda, int ldb, int ldc)
{ gemm_body<2>(Abf, xg, shiftg, ma, mg, Bt, Cf, Cb, K, lda, ldb, ldc); }

__global__ __launch_bounds__(256) void k_gemm_s2(
  const u16* Abf, const float* xg, const float* shiftg, const float* ma, const float* mg,
  const u16* Bt, float* Cf, u16* Cb, int K, int lda, int ldb, int ldc)
{ gemm_body<3>(Abf, xg, shiftg, ma, mg, Bt, Cf, Cb, K, lda, ldb, ldc); }

__global__ __launch_bounds__(256) void k_gemm_fin(
  const u16* Abf, const float* xg, const float* shiftg, const float* ma, const float* mg,
  const u16* Bt, float* Cf, u16* Cb, int K, int lda, int ldb, int ldc)
{ gemm_body<0>(Abf, xg, shiftg, ma, mg, Bt, Cf, Cb, K, lda, ldb, ldc); }

// ---------- post1 ----------
__global__ __launch_bounds__(256) void k_post1(
  u16* __restrict__ kb, u16* __restrict__ vb, const u16* __restrict__ winb,
  u16* __restrict__ ainb, u16* __restrict__ vinb,
  const float* __restrict__ vfirst,
  const float* __restrict__ w0, const float* __restrict__ a0, const float* __restrict__ v0,
  const float* __restrict__ kkv, const float* __restrict__ kav,
  float* __restrict__ dec)
{
  int grp = blockIdx.x*4 + (threadIdx.x >> 6);
  int n = threadIdx.x & 63;
  int i = grp >> 5, h = grp & 31;
  int c = h*64 + n;
  size_t idx = (size_t)i*CC + c;
  float k  = bf2f(kb[idx]),  v = bf2f(vb[idx]);
  float wi = bf2f(winb[idx]), ai = bf2f(ainb[idx]), vi = bf2f(vinb[idx]);
  float vf = vfirst[idx];
  float a  = 1.f/(1.f + expf(-(a0[c] + ai)));
  float z  = -(w0[c] + wi);
  float sp = (z > 15.f) ? z : log1pf(expf(z));
  float decay = expf(-expf(-sp - 0.5f));
  float vg = 1.f/(1.f + expf(-(v0[c] + vi)));
  float vfin = v + (vf - v)*vg;
  float kkr = k * kkv[c];
  float ss = wave_sum64(kkr*kkr);
  float kkn = kkr / fmaxf(sqrtf(ss), 1e-12f);
  float kfin = k * (1.f + (a - 1.f)*kav[c]);
  kb[idx] = f2bf(kfin);
  vb[idx] = f2bf(vfin);
  dec[idx] = decay;
  vinb[idx] = f2bf(kkn);
  ainb[idx] = f2bf(-(kkn * a));
}

// ---------- WKV scan v6: asm-pinned prefetch, 2 x 8-step chunks, counted vmcnt ----------
// 1024 blocks = 8 row-octets x 128 (b,h); XCD(blk%8)=bh%8 keeps octets of a bh on one L2.
// Lane (rg,cg): rows {oct*8+rg*2, +1}, cols cg*4..+3. Loads via volatile asm (cannot be
// sunk by the scheduler); chunk's 48 loads stay in flight across the other chunk's math.
// vmcnt ledger (in-order retirement): steady wait = 48 younger loads + 8 y-stores = 56.
#define SDECL(S) float4 w##S[8]; u32x2 b##S[8], k##S[8], kk##S[8], r##S[8]; u32 v##S[8];

#define SISSUE(S, t0) do {                                                        \
  _Pragma("unroll")                                                               \
  for (int s_=0; s_<8; ++s_){                                                     \
    u64 ow = (u64)(uintptr_t)&wb [gc0 + (size_t)((t0)+s_)*CC];                    \
    u64 ob = (u64)(uintptr_t)&bbp[gc0 + (size_t)((t0)+s_)*CC];                    \
    u64 ok = (u64)(uintptr_t)&kb [gc0 + (size_t)((t0)+s_)*CC];                    \
    u64 oq = (u64)(uintptr_t)&kkb[gc0 + (size_t)((t0)+s_)*CC];                    \
    u64 orr= (u64)(uintptr_t)&rb [gc0 + (size_t)((t0)+s_)*CC];                    \
    u64 ov = (u64)(uintptr_t)&vb [gv0 + (size_t)((t0)+s_)*CC];                    \
    asm volatile("global_load_dwordx4 %0, %1, off" : "=v"(w##S[s_])  : "v"(ow) : "memory"); \
    asm volatile("global_load_dwordx2 %0, %1, off" : "=v"(b##S[s_])  : "v"(ob) : "memory"); \
    asm volatile("global_load_dwordx2 %0, %1, off" : "=v"(k##S[s_])  : "v"(ok) : "memory"); \
    asm volatile("global_load_dwordx2 %0, %1, off" : "=v"(kk##S[s_]) : "v"(oq) : "memory"); \
    asm volatile("global_load_dwordx2 %0, %1, off" : "=v"(r##S[s_])  : "v"(orr): "memory"); \
    asm volatile("global_load_dword   %0, %1, off" : "=v"(v##S[s_])  : "v"(ov) : "memory"); \
  }                                                                               \
} while(0)

#define SCHUNK(S, t0, CNT) do {                                                   \
  asm volatile("s_waitcnt vmcnt(" #CNT ")" ::: "memory");                         \
  __builtin_amdgcn_sched_barrier(0);                                              \
  _Pragma("unroll")                                                               \
  for (int s_=0; s_<8; ++s_){                                                     \
    const float w_0=w##S[s_].x, w_1=w##S[s_].y, w_2=w##S[s_].z, w_3=w##S[s_].w;   \
    const float b_0=bflo(b##S[s_].x), b_1=bfhi(b##S[s_].x),                       \
                b_2=bflo(b##S[s_].y), b_3=bfhi(b##S[s_].y);                       \
    const float k_0=bflo(k##S[s_].x), k_1=bfhi(k##S[s_].x),                       \
                k_2=bflo(k##S[s_].y), k_3=bfhi(k##S[s_].y);                       \
    const float q_0=bflo(kk##S[s_].x), q_1=bfhi(kk##S[s_].x),                     \
                q_2=bflo(kk##S[s_].y), q_3=bfhi(kk##S[s_].y);                     \
    const float r_0=bflo(r##S[s_].x), r_1=bfhi(r##S[s_].x),                       \
                r_2=bflo(r##S[s_].y), r_3=bfhi(r##S[s_].y);                       \
    const float vv0_ = bflo(v##S[s_]);                                            \
    const float vv1_ = bfhi(v##S[s_]);                                            \
    float p0_ = fmaf(st[0][0],q_0, st[0][1]*q_1) + fmaf(st[0][2],q_2, st[0][3]*q_3); \
    float p1_ = fmaf(st[1][0],q_0, st[1][1]*q_1) + fmaf(st[1][2],q_2, st[1][3]*q_3); \
    p0_ = red16(p0_); p1_ = red16(p1_);                                           \
    st[0][0] = fmaf(st[0][0],w_0, fmaf(p0_,b_0, vv0_*k_0));                       \
    st[0][1] = fmaf(st[0][1],w_1, fmaf(p0_,b_1, vv0_*k_1));                       \
    st[0][2] = fmaf(st[0][2],w_2, fmaf(p0_,b_2, vv0_*k_2));                       \
    st[0][3] = fmaf(st[0][3],w_3, fmaf(p0_,b_3, vv0_*k_3));                       \
    st[1][0] = fmaf(st[1][0],w_0, fmaf(p1_,b_0, vv1_*k_0));                       \
    st[1][1] = fmaf(st[1][1],w_1, fmaf(p1_,b_1, vv1_*k_1));                       \
    st[1][2] = fmaf(st[1][2],w_2, fmaf(p1_,b_2, vv1_*k_2));                       \
    st[1][3] = fmaf(st[1][3],w_3, fmaf(p1_,b_3, vv1_*k_3));                       \
    float y0_ = fmaf(st[0][0],r_0, st[0][1]*r_1) + fmaf(st[0][2],r_2, st[0][3]*r_3); \
    float y1_ = fmaf(st[1][0],r_0, st[1][1]*r_1) + fmaf(st[1][2],r_2, st[1][3]*r_3); \
    y0_ = red16(y0_); y1_ = red16(y1_);                                           \
    if (cg == 0){                                                                 \
      u32 pk_ = (u32)f2bf(y0_) | ((u32)f2bf(y1_) << 16);                          \
      *(u32*)&yb[gv0 + (size_t)((t0)+s_)*CC] = pk_;                               \
    }                                                                             \
  }                                                                               \
} while(0)

__global__ __launch_bounds__(64, 1) void k_scan(
  const u16* __restrict__ rb, const float* __restrict__ wb,
  const u16* __restrict__ kb, const u16* __restrict__ vb,
  const u16* __restrict__ kkb, const u16* __restrict__ bbp,
  const float* __restrict__ wkv_in, u16* __restrict__ yb, float* __restrict__ wkv_out)
{
  const int blk = blockIdx.x;
  const int bh = blk & 127, oct = blk >> 7;
  const int b = bh >> 5, h = bh & 31;
  const int ln = threadIdx.x;
  const int rg = ln >> 4;
  const int cg = ln & 15;
  const int row0 = oct*8 + rg*2;
  const int col0 = cg*4;

  float st[2][4];
  {
    const float* sp0 = &wkv_in[((size_t)bh*64 + row0    )*64 + col0];
    const float* sp1 = &wkv_in[((size_t)bh*64 + row0 + 1)*64 + col0];
    float4 a = *(const float4*)sp0, c = *(const float4*)sp1;
    st[0][0]=a.x; st[0][1]=a.y; st[0][2]=a.z; st[0][3]=a.w;
    st[1][0]=c.x; st[1][1]=c.y; st[1][2]=c.z; st[1][3]=c.w;
  }

  const size_t gc0 = ((size_t)b*TT)*CC + h*64 + col0;
  const size_t gv0 = ((size_t)b*TT)*CC + h*64 + row0;

  SDECL(A) SDECL(B)

  SISSUE(A, 0);
  SISSUE(B, 8);
  // peel c=0: A not yet shadowed by stores -> vmcnt(48); B shadowed by 8 stores + 48 loads
  SCHUNK(A, 0, 48);
  SISSUE(A, 16);
  SCHUNK(B, 8, 56);
  SISSUE(B, 24);
  for (int c = 1; c < 63; ++c){
    const int t0 = c*16;
    SCHUNK(A, t0, 56);
    SISSUE(A, t0+16);
    SCHUNK(B, t0+8, 56);
    SISSUE(B, t0+24);
  }
  // tail c=63
  SCHUNK(A, 1008, 56);
  SCHUNK(B, 1016, 0);

  {
    float* wo0 = &wkv_out[((size_t)bh*64 + row0    )*64 + col0];
    float* wo1 = &wkv_out[((size_t)bh*64 + row0 + 1)*64 + col0];
    *(float4*)wo0 = make_float4(st[0][0], st[0][1], st[0][2], st[0][3]);
    *(float4*)wo1 = make_float4(st[1][0], st[1][1], st[1][2], st[1][3]);
  }
}

// ---------- post2 ----------
__global__ __launch_bounds__(256) void k_post2(
  const u16* __restrict__ ybuf, const u16* __restrict__ rbuf,
  const u16* __restrict__ kfb, const u16* __restrict__ vfb,
  const u16* __restrict__ gbuf, const float* __restrict__ rk,
  const float* __restrict__ lnw, const float* __restrict__ lnb, u16* __restrict__ ao)
{
  int grp = blockIdx.x*4 + (threadIdx.x >> 6);
  int n = threadIdx.x & 63;
  int i = grp >> 5, h = grp & 31;
  int c = h*64 + n;
  size_t idx = (size_t)i*CC + c;
  float y = bf2f(ybuf[idx]);
  float s1 = wave_sum64(y);
  float s2 = wave_sum64(y*y);
  float mu = s1 * (1.f/64.f);
  float var = s2 * (1.f/64.f) - mu*mu;
  float yn = (y - mu) * rsqrtf(var + 6.4e-4f) * lnw[c] + lnb[c];
  float rv = bf2f(rbuf[idx]), kv = bf2f(kfb[idx]);
  float s3 = wave_sum64(rv * kv * rk[c]);
  float bonus = s3 * bf2f(vfb[idx]);
  ao[idx] = f2bf((yn + bonus) * bf2f(gbuf[idx]));
}

// ---------- shift_state_out ----------
__global__ __launch_bounds__(256) void k_shift(const float* __restrict__ x, float* __restrict__ so){
  int i = blockIdx.x*256 + threadIdx.x;
  int b = i >> 9, c4 = (i & 511)*4;
  *(float4*)&so[(size_t)b*CC + c4] = *(const float4*)&x[((size_t)(b*TT + TT-1))*CC + c4];
}

// ---------- launch ----------
extern "C" void kernel_launch(void* const* d_in, const int* in_sizes, int n_in,
                              void* d_out, int out_size, void* d_ws, size_t ws_size,
                              hipStream_t stream)
{
  const float* x        = (const float*)d_in[0];
  const float* shift_in = (const float*)d_in[1];
  const float* wkv_in   = (const float*)d_in[2];
  const float* v_first  = (const float*)d_in[3];
  const float* x_r = (const float*)d_in[4];
  const float* x_w = (const float*)d_in[5];
  const float* x_k = (const float*)d_in[6];
  const float* x_v = (const float*)d_in[7];
  const float* x_a = (const float*)d_in[8];
  const float* x_g = (const float*)d_in[9];
  const float* w0 = (const float*)d_in[10];
  const float* w1 = (const float*)d_in[11];
  const float* w2 = (const float*)d_in[12];
  const float* a0 = (const float*)d_in[13];
  const float* a1 = (const float*)d_in[14];
  const float* a2 = (const float*)d_in[15];
  const float* v0 = (const float*)d_in[16];
  const float* v1 = (const float*)d_in[17];
  const float* v2 = (const float*)d_in[18];
  const float* g1 = (const float*)d_in[19];
  const float* g2 = (const float*)d_in[20];
  const float* k_k = (const float*)d_in[21];
  const float* k_a = (const float*)d_in[22];
  const float* r_k = (const float*)d_in[23];
  const float* Wr = (const float*)d_in[24];
  const float* Wk = (const float*)d_in[25];
  const float* Wv = (const float*)d_in[26];
  const float* Wo = (const float*)d_in[27];
  const float* ln_w = (const float*)d_in[28];
  const float* ln_b = (const float*)d_in[29];

  // ---- ws layout ----
  char* ws = (char*)d_ws;
  u16* WOB  = (u16*)(ws + 0);
  u16* WRB  = (u16*)(ws + 8388608);
  u16* B2W  = (u16*)(ws + 36175872);
  u16* PBUF = (u16*)(ws + 38797312);
  u16* RB   = (u16*)(ws + 44040192);
  u16* KB   = (u16*)(ws + 60817408);
  u16* VB   = (u16*)(ws + 77594624);
  u16* YB   = (u16*)(ws + 94371840);
  float* DEC  = (float*)(ws + 8388608);
  u16* AO   = (u16*)(ws + 8388608);

  // ---- d_out scratch ----
  float* out       = (float*)d_out;
  float* shift_out = out + 8388608;
  float* wkv_out   = out + 8396800;
  float* vf_out    = out + 8921088;
  u16* XRKV = (u16*)d_out;
  u16* WINb = (u16*)d_out;
  u16* AINb = (u16*)((char*)d_out + 16777216);
  u16* VINb = (u16*)((char*)d_out + 35684352);

  // weight prep
  k_cast4<<<16384, 256, 0, stream>>>(Wr, Wk, Wv, Wo, (u16*)ws);
  k_tpadA<<<2560, 256, 0, stream>>>(w1, a1, v1, g1, w2, a2, v2, g2, (u16*)ws);

  // token-shift mix precompute
  k_prep4<<<8192, 256, 0, stream>>>(x, shift_in, x_r, x_k, x_v, x_w,
                                    XRKV, XRKV + 8388608u, XRKV + 16777216u, XRKV + 25165824u);

  // fused r/k/v + stage-1 GEMM
  k_gemm_rkv<<<dim3(53,32), 256, 0, stream>>>(XRKV, x, shift_in, x_a, x_g,
                                              WRB, (float*)PBUF, RB, 2048, 2048, 2048, 2048);

  // fused stage-2 GEMMs
  k_gemm_s2<<<dim3(64,32), 256, 0, stream>>>(PBUF, nullptr, nullptr, nullptr, nullptr,
                                             B2W, nullptr, (u16*)d_out, 0, 640, 128, 2048);

  // elementwise post
  k_post1<<<32768, 256, 0, stream>>>(KB, VB, WINb, AINb, VINb, v_first,
                                     w0, a0, v0, k_k, k_a, DEC);

  // sequential WKV scan (asm-pinned prefetch)
  k_scan<<<1024, 64, 0, stream>>>(RB, DEC, KB, VB, VINb, AINb, wkv_in, YB, wkv_out);

  // groupnorm + bonus + gate
  k_post2<<<32768, 256, 0, stream>>>(YB, RB, KB, VB, (u16*)((char*)d_out + 52461568),
                                     r_k, ln_w, ln_b, AO);

  // final GEMM -> out
  k_gemm_fin<<<dim3(16,32), 256, 0, stream>>>(AO, nullptr, nullptr, nullptr, nullptr,
                                              WOB, out, nullptr, 2048, 2048, 2048, 2048);

  // small outputs last
  k_shift<<<8, 256, 0, stream>>>(x, shift_out);
  hipMemcpyAsync(vf_out, v_first, 33554432, hipMemcpyDeviceToDevice, stream);
}

// Round 13
// 686.754 us; speedup vs baseline: 1.4368x; 1.0686x over previous
//
#include <hip/hip_runtime.h>
#include <hip/hip_bf16.h>
#include <stdint.h>

typedef unsigned short u16;
typedef unsigned int u32;
typedef unsigned long long u64;
typedef __attribute__((ext_vector_type(8))) short short8;
typedef __attribute__((ext_vector_type(4))) float f32x4;
typedef __attribute__((ext_vector_type(2))) unsigned int u32x2;

#define BB 4
#define TT 1024
#define CC 2048

// ---------- helpers ----------
__device__ __forceinline__ u16 f2bf(float f){
  __hip_bfloat16 h = __float2bfloat16(f);
  return *reinterpret_cast<u16*>(&h);
}
__device__ __forceinline__ float bf2f(u16 h){
  union { u32 u; float f; } v; v.u = ((u32)h) << 16; return v.f;
}
__device__ __forceinline__ float bflo(u32 p){
  union { u32 u; float f; } v; v.u = p << 16; return v.f;
}
__device__ __forceinline__ float bfhi(u32 p){
  union { u32 u; float f; } v; v.u = p & 0xFFFF0000u; return v.f;
}

__device__ __forceinline__ void gload16(const void* g, void* s){
  __builtin_amdgcn_global_load_lds((const __attribute__((address_space(1))) u32*)g,
                                   (__attribute__((address_space(3))) u32*)s, 16, 0, 0);
}

__device__ __forceinline__ float wave_sum64(float x){
  #pragma unroll
  for (int m = 1; m < 64; m <<= 1) x += __shfl_xor(x, m, 64);
  return x;
}

template<int N>
__device__ __forceinline__ float ror_add(float x){
  int t = __builtin_amdgcn_update_dpp(0, __builtin_bit_cast(int, x), 0x120 | N, 0xF, 0xF, false);
  return x + __builtin_bit_cast(float, t);
}
__device__ __forceinline__ float red16(float x){
  x = ror_add<8>(x); x = ror_add<4>(x); x = ror_add<2>(x); x = ror_add<1>(x);
  return x;
}

// Bijective XCD-chunked swizzle (m204), bx-major within an A-row-panel.
__device__ __forceinline__ void xcd_map(int nx, int& bx, int& row0){
  const int G = gridDim.x;
  const int q = G >> 3, r = G & 7;
  const int xcd = blockIdx.x & 7, i2 = blockIdx.x >> 3;
  const int sw = (xcd < r) ? (xcd*(q+1) + i2) : (r*(q+1) + (xcd - r)*q + i2);
  const int by = sw / nx;
  bx = sw - by*nx;
  row0 = by * 128;
}

// ---------- fused weight casts ----------
__global__ __launch_bounds__(256) void k_cast4(
  const float* __restrict__ wr, const float* __restrict__ wk,
  const float* __restrict__ wv, const float* __restrict__ wo,
  u16* __restrict__ wsb)
{
  int i = blockIdx.x*256 + threadIdx.x;
  int seg = i >> 20;
  int off = (i & 1048575) * 4;
  const float* src = (seg==0) ? wr : (seg==1) ? wk : (seg==2) ? wv : wo;
  const size_t dofs = (seg==0) ? 4194304u : (seg==1) ? 8388608u : (seg==2) ? 12582912u : 0u;
  float4 v = *(const float4*)&src[off];
  *(ushort4*)&wsb[dofs + off] = make_ushort4(f2bf(v.x), f2bf(v.y), f2bf(v.z), f2bf(v.w));
}

// ---------- fused tiled transposes ----------
__global__ __launch_bounds__(256) void k_tpadA(
  const float* __restrict__ w1, const float* __restrict__ a1,
  const float* __restrict__ v1, const float* __restrict__ g1,
  const float* __restrict__ w2, const float* __restrict__ a2,
  const float* __restrict__ v2, const float* __restrict__ g2,
  u16* __restrict__ wsb)
{
  __shared__ float lds[32][33];
  const int blk = blockIdx.x;
  const float* src; int R, S, Rpad, tile, tiles_r; size_t dst;
  if      (blk <  256){ src=w1; R=2048; S=96;   Rpad=2048; dst=16777216u; tile=blk;      tiles_r=64; }
  else if (blk <  512){ src=a1; R=2048; S=96;   Rpad=2048; dst=17039360u; tile=blk-256;  tiles_r=64; }
  else if (blk <  768){ src=v1; R=2048; S=64;   Rpad=2048; dst=17301504u; tile=blk-512;  tiles_r=64; }
  else if (blk < 1280){ src=g1; R=2048; S=256;  Rpad=2048; dst=17563648u; tile=blk-768;  tiles_r=64; }
  else if (blk < 1536){ src=w2; R=96;   S=2048; Rpad=128;  dst=18087936u; tile=blk-1280; tiles_r=4;  }
  else if (blk < 1792){ src=a2; R=96;   S=2048; Rpad=128;  dst=18350080u; tile=blk-1536; tiles_r=4;  }
  else if (blk < 2048){ src=v2; R=64;   S=2048; Rpad=128;  dst=18612224u; tile=blk-1792; tiles_r=4;  }
  else                { src=g2; R=256;  S=2048; Rpad=256;  dst=18874368u; tile=blk-2048; tiles_r=8;  }
  const int tr = tile % tiles_r, ts = tile / tiles_r;
  const int r0 = tr*32, s0 = ts*32;
  const int tj = threadIdx.x & 31, ti = threadIdx.x >> 5;
  #pragma unroll
  for (int p=0;p<4;p++){
    int rr = r0 + p*8 + ti, ss = s0 + tj;
    lds[p*8+ti][tj] = (rr < R && ss < S) ? src[(size_t)rr*S + ss] : 0.f;
  }
  __syncthreads();
  #pragma unroll
  for (int p=0;p<4;p++){
    int sl = p*8 + ti, rl = tj;
    wsb[dst + (size_t)(s0+sl)*Rpad + r0 + rl] = f2bf(lds[rl][sl]);
  }
}

// ---------- prep: token-shift mix -> XR,XK,XV,XW bf16 ----------
__global__ __launch_bounds__(256) void k_prep4(
  const float* __restrict__ x, const float* __restrict__ shift_in,
  const float* __restrict__ mr, const float* __restrict__ mk,
  const float* __restrict__ mv, const float* __restrict__ mw,
  u16* __restrict__ xr, u16* __restrict__ xk, u16* __restrict__ xv, u16* __restrict__ xw)
{
  int idx = blockIdx.x*256 + threadIdx.x;
  int c4 = (idx & 511) * 4;
  int t  = (idx >> 9) & (TT-1);
  int b  = idx >> 19;
  size_t xo = ((size_t)(b*TT + t))*CC + c4;
  float4 xc = *(const float4*)&x[xo];
  float4 xp = (t == 0) ? *(const float4*)&shift_in[(size_t)b*CC + c4]
                       : *(const float4*)&x[xo - CC];
  float d0 = xp.x-xc.x, d1 = xp.y-xc.y, d2 = xp.z-xc.z, d3 = xp.w-xc.w;
#define MIXO(mp, op) { float4 m = *(const float4*)&mp[c4]; \
    *(ushort4*)&op[xo] = make_ushort4(f2bf(fmaf(d0,m.x,xc.x)), f2bf(fmaf(d1,m.y,xc.y)), \
                                      f2bf(fmaf(d2,m.z,xc.z)), f2bf(fmaf(d3,m.w,xc.w))); }
  MIXO(mr, xr); MIXO(mk, xk); MIXO(mv, xv); MIXO(mw, xw);
#undef MIXO
}

// ---------- GEMM body (device); 1D grid + XCD-chunked swizzle ----------
template<int AMODE>
__device__ __forceinline__ void gemm_body(
  const u16* __restrict__ Abf,
  const float* __restrict__ xg, const float* __restrict__ shiftg,
  const float* __restrict__ ma, const float* __restrict__ mg,
  const u16* __restrict__ Bt, float* __restrict__ Cf, u16* __restrict__ Cb,
  int K, int lda, int ldb, int ldc, int nx)
{
  __shared__ alignas(16) u16 sA[128*32];
  __shared__ alignas(16) u16 sB[128*32];
  const int tid = threadIdx.x;
  const int wv = tid >> 6, ln = tid & 63;
  int bx, row0;
  xcd_map(nx, bx, row0);
  const int wr = wv >> 1, wc = wv & 1;

  const float* mixv = nullptr;
  const u16* Ap = Abf;
  const u16* Btp = Bt;
  u16* Cbp = Cb;
  bool bmix = false;
  int bcol0 = bx * 128;
  int ccol0 = bx * 128;
  int ldaa = lda, ldbb = ldb, ldcc = ldc;
  int KK = K, act = 0;

  if (AMODE == 2){
    if (bx < 48){
      int sel = bx >> 4;
      Ap = Abf + (size_t)sel * 8388608u;
      Cbp = Cb + (size_t)sel * 8388608u;
      ccol0 = (bx & 15) * 128;
      ldcc = 2048; ldaa = 2048;
    } else {
      int sb = bx - 48;
      Cbp = (u16*)Cf;
      ccol0 = sb * 128;
      ldcc = 640;
      act = (sb==0) ? 1 : (sb>=3 ? 2 : 0);
      if (sb == 0){ Ap = Abf + 25165824u; ldaa = 2048; }
      else if (sb == 2){ Ap = Abf + 16777216u; ldaa = 2048; }
      else { bmix = true; mixv = (sb==1) ? ma : mg; }
    }
  }
  if (AMODE == 3){
    int sel = bx >> 4;
    Ap = Abf + sel*128;
    Btp = Bt + (size_t)sel * 262144u;
    ldbb = (sel==3) ? 256 : 128;
    KK = (sel==3) ? 256 : 128;
    const int coffs[4] = {0, 8388608, 17842176, 26230784};
    Cbp = Cb + coffs[sel];
    ccol0 = (bx & 15) * 128;
    bcol0 = ccol0;
    ldcc = 2048;
  }

  f32x4 acc[4][4] = {};
  const int ob0 = wv*2048;
  const int o0  = ob0 + ln*16;
  const int rA0 = o0 >> 6;
  const int ke0 = (o0 & 63) >> 1;
  const int ar  = tid >> 2;
  const int akc = (tid & 3) * 8;

  for (int k0 = 0; k0 < KK; k0 += 32){
    __syncthreads();
    if (AMODE != 2 || !bmix){
      gload16(&Ap[(size_t)(row0 + rA0     )*ldaa + k0 + ke0], (void*)((char*)sA + ob0));
      gload16(&Ap[(size_t)(row0 + rA0 + 16)*ldaa + k0 + ke0], (void*)((char*)sA + ob0 + 1024));
    }
    gload16(&Btp[(size_t)(bcol0 + rA0     )*ldbb + k0 + ke0], (void*)((char*)sB + ob0));
    gload16(&Btp[(size_t)(bcol0 + rA0 + 16)*ldbb + k0 + ke0], (void*)((char*)sB + ob0 + 1024));
    if (AMODE == 2 && bmix){
      float4 m0 = *(const float4*)&mixv[k0 + akc];
      float4 m1 = *(const float4*)&mixv[k0 + akc + 4];
      #pragma unroll
      for (int it = 0; it < 2; ++it){
        int r = ar + it*64;
        int gr = row0 + r;
        size_t xo = (size_t)gr*CC + k0 + akc;
        float4 c0 = *(const float4*)&xg[xo];
        float4 c1 = *(const float4*)&xg[xo + 4];
        const float* pp = ((gr & (TT-1)) == 0) ? &shiftg[(size_t)(gr >> 10)*CC + k0 + akc]
                                               : &xg[xo - CC];
        float4 p0 = *(const float4*)&pp[0];
        float4 p1 = *(const float4*)&pp[4];
        short8 vvv;
        vvv[0] = (short)f2bf(c0.x + (p0.x - c0.x)*m0.x);
        vvv[1] = (short)f2bf(c0.y + (p0.y - c0.y)*m0.y);
        vvv[2] = (short)f2bf(c0.z + (p0.z - c0.z)*m0.z);
        vvv[3] = (short)f2bf(c0.w + (p0.w - c0.w)*m0.w);
        vvv[4] = (short)f2bf(c1.x + (p1.x - c1.x)*m1.x);
        vvv[5] = (short)f2bf(c1.y + (p1.y - c1.y)*m1.y);
        vvv[6] = (short)f2bf(c1.z + (p1.z - c1.z)*m1.z);
        vvv[7] = (short)f2bf(c1.w + (p1.w - c1.w)*m1.w);
        *(short8*)&sA[r*32 + akc] = vvv;
      }
    }
    __syncthreads();
    short8 aF[4], bF[4];
    #pragma unroll
    for (int m=0;m<4;m++) aF[m] = *(const short8*)&sA[(wr*64 + m*16 + (ln&15))*32 + (ln>>4)*8];
    #pragma unroll
    for (int n=0;n<4;n++) bF[n] = *(const short8*)&sB[(wc*64 + n*16 + (ln&15))*32 + (ln>>4)*8];
    #pragma unroll
    for (int m=0;m<4;m++)
      #pragma unroll
      for (int n=0;n<4;n++)
        acc[m][n] = __builtin_amdgcn_mfma_f32_16x16x32_bf16(aF[m], bF[n], acc[m][n], 0,0,0);
  }

  const int cr = (ln >> 4) * 4, ccol = ln & 15;
  #pragma unroll
  for (int m=0;m<4;m++){
    #pragma unroll
    for (int n=0;n<4;n++){
      int gc = ccol0 + wc*64 + n*16 + ccol;
      #pragma unroll
      for (int j=0;j<4;j++){
        int gr = row0 + wr*64 + m*16 + cr + j;
        float v = acc[m][n][j];
        if (AMODE == 0){
          Cf[(size_t)gr*ldcc + gc] = v;
        } else {
          if (act == 1) v = tanhf(v);
          else if (act == 2) v = 1.f/(1.f + expf(-v));
          Cbp[(size_t)gr*ldcc + gc] = f2bf(v);
        }
      }
    }
  }
}

// named wrappers
__global__ __launch_bounds__(256) void k_gemm_rkv(
  const u16* Abf, const float* xg, const float* shiftg, const float* ma, const float* mg,
  const u16* Bt, float* Cf, u16* Cb, int K, int lda, int ldb, int ldc, int nx)
{ gemm_body<2>(Abf, xg, shiftg, ma, mg, Bt, Cf, Cb, K, lda, ldb, ldc, nx); }

__global__ __launch_bounds__(256) void k_gemm_s2(
  const u16* Abf, const float* xg, const float* shiftg, const float* ma, const float* mg,
  const u16* Bt, float* Cf, u16* Cb, int K, int lda, int ldb, int ldc, int nx)
{ gemm_body<3>(Abf, xg, shiftg, ma, mg, Bt, Cf, Cb, K, lda, ldb, ldc, nx); }

__global__ __launch_bounds__(256) void k_gemm_fin(
  const u16* Abf, const float* xg, const float* shiftg, const float* ma, const float* mg,
  const u16* Bt, float* Cf, u16* Cb, int K, int lda, int ldb, int ldc, int nx)
{ gemm_body<0>(Abf, xg, shiftg, ma, mg, Bt, Cf, Cb, K, lda, ldb, ldc, nx); }

// ---------- post1 ----------
__global__ __launch_bounds__(256) void k_post1(
  u16* __restrict__ kb, u16* __restrict__ vb, const u16* __restrict__ winb,
  u16* __restrict__ ainb, u16* __restrict__ vinb,
  const float* __restrict__ vfirst,
  const float* __restrict__ w0, const float* __restrict__ a0, const float* __restrict__ v0,
  const float* __restrict__ kkv, const float* __restrict__ kav,
  float* __restrict__ dec)
{
  int grp = blockIdx.x*4 + (threadIdx.x >> 6);
  int n = threadIdx.x & 63;
  int i = grp >> 5, h = grp & 31;
  int c = h*64 + n;
  size_t idx = (size_t)i*CC + c;
  float k  = bf2f(kb[idx]),  v = bf2f(vb[idx]);
  float wi = bf2f(winb[idx]), ai = bf2f(ainb[idx]), vi = bf2f(vinb[idx]);
  float vf = vfirst[idx];
  float a  = 1.f/(1.f + expf(-(a0[c] + ai)));
  float z  = -(w0[c] + wi);
  float sp = (z > 15.f) ? z : log1pf(expf(z));
  float decay = expf(-expf(-sp - 0.5f));
  float vg = 1.f/(1.f + expf(-(v0[c] + vi)));
  float vfin = v + (vf - v)*vg;
  float kkr = k * kkv[c];
  float ss = wave_sum64(kkr*kkr);
  float kkn = kkr / fmaxf(sqrtf(ss), 1e-12f);
  float kfin = k * (1.f + (a - 1.f)*kav[c]);
  kb[idx] = f2bf(kfin);
  vb[idx] = f2bf(vfin);
  dec[idx] = decay;
  vinb[idx] = f2bf(kkn);
  ainb[idx] = f2bf(-(kkn * a));
}

// ---------- WKV scan v6: asm-pinned prefetch, 2 x 8-step chunks, counted vmcnt ----------
#define SDECL(S) float4 w##S[8]; u32x2 b##S[8], k##S[8], kk##S[8], r##S[8]; u32 v##S[8];

#define SISSUE(S, t0) do {                                                        \
  _Pragma("unroll")                                                               \
  for (int s_=0; s_<8; ++s_){                                                     \
    u64 ow = (u64)(uintptr_t)&wb [gc0 + (size_t)((t0)+s_)*CC];                    \
    u64 ob = (u64)(uintptr_t)&bbp[gc0 + (size_t)((t0)+s_)*CC];                    \
    u64 ok = (u64)(uintptr_t)&kb [gc0 + (size_t)((t0)+s_)*CC];                    \
    u64 oq = (u64)(uintptr_t)&kkb[gc0 + (size_t)((t0)+s_)*CC];                    \
    u64 orr= (u64)(uintptr_t)&rb [gc0 + (size_t)((t0)+s_)*CC];                    \
    u64 ov = (u64)(uintptr_t)&vb [gv0 + (size_t)((t0)+s_)*CC];                    \
    asm volatile("global_load_dwordx4 %0, %1, off" : "=v"(w##S[s_])  : "v"(ow) : "memory"); \
    asm volatile("global_load_dwordx2 %0, %1, off" : "=v"(b##S[s_])  : "v"(ob) : "memory"); \
    asm volatile("global_load_dwordx2 %0, %1, off" : "=v"(k##S[s_])  : "v"(ok) : "memory"); \
    asm volatile("global_load_dwordx2 %0, %1, off" : "=v"(kk##S[s_]) : "v"(oq) : "memory"); \
    asm volatile("global_load_dwordx2 %0, %1, off" : "=v"(r##S[s_])  : "v"(orr): "memory"); \
    asm volatile("global_load_dword   %0, %1, off" : "=v"(v##S[s_])  : "v"(ov) : "memory"); \
  }                                                                               \
} while(0)

#define SCHUNK(S, t0, CNT) do {                                                   \
  asm volatile("s_waitcnt vmcnt(" #CNT ")" ::: "memory");                         \
  __builtin_amdgcn_sched_barrier(0);                                              \
  _Pragma("unroll")                                                               \
  for (int s_=0; s_<8; ++s_){                                                     \
    const float w_0=w##S[s_].x, w_1=w##S[s_].y, w_2=w##S[s_].z, w_3=w##S[s_].w;   \
    const float b_0=bflo(b##S[s_].x), b_1=bfhi(b##S[s_].x),                       \
                b_2=bflo(b##S[s_].y), b_3=bfhi(b##S[s_].y);                       \
    const float k_0=bflo(k##S[s_].x), k_1=bfhi(k##S[s_].x),                       \
                k_2=bflo(k##S[s_].y), k_3=bfhi(k##S[s_].y);                       \
    const float q_0=bflo(kk##S[s_].x), q_1=bfhi(kk##S[s_].x),                     \
                q_2=bflo(kk##S[s_].y), q_3=bfhi(kk##S[s_].y);                     \
    const float r_0=bflo(r##S[s_].x), r_1=bfhi(r##S[s_].x),                       \
                r_2=bflo(r##S[s_].y), r_3=bfhi(r##S[s_].y);                       \
    const float vv0_ = bflo(v##S[s_]);                                            \
    const float vv1_ = bfhi(v##S[s_]);                                            \
    float p0_ = fmaf(st[0][0],q_0, st[0][1]*q_1) + fmaf(st[0][2],q_2, st[0][3]*q_3); \
    float p1_ = fmaf(st[1][0],q_0, st[1][1]*q_1) + fmaf(st[1][2],q_2, st[1][3]*q_3); \
    p0_ = red16(p0_); p1_ = red16(p1_);                                           \
    st[0][0] = fmaf(st[0][0],w_0, fmaf(p0_,b_0, vv0_*k_0));                       \
    st[0][1] = fmaf(st[0][1],w_1, fmaf(p0_,b_1, vv0_*k_1));                       \
    st[0][2] = fmaf(st[0][2],w_2, fmaf(p0_,b_2, vv0_*k_2));                       \
    st[0][3] = fmaf(st[0][3],w_3, fmaf(p0_,b_3, vv0_*k_3));                       \
    st[1][0] = fmaf(st[1][0],w_0, fmaf(p1_,b_0, vv1_*k_0));                       \
    st[1][1] = fmaf(st[1][1],w_1, fmaf(p1_,b_1, vv1_*k_1));                       \
    st[1][2] = fmaf(st[1][2],w_2, fmaf(p1_,b_2, vv1_*k_2));                       \
    st[1][3] = fmaf(st[1][3],w_3, fmaf(p1_,b_3, vv1_*k_3));                       \
    float y0_ = fmaf(st[0][0],r_0, st[0][1]*r_1) + fmaf(st[0][2],r_2, st[0][3]*r_3); \
    float y1_ = fmaf(st[1][0],r_0, st[1][1]*r_1) + fmaf(st[1][2],r_2, st[1][3]*r_3); \
    y0_ = red16(y0_); y1_ = red16(y1_);                                           \
    if (cg == 0){                                                                 \
      u32 pk_ = (u32)f2bf(y0_) | ((u32)f2bf(y1_) << 16);                          \
      *(u32*)&yb[gv0 + (size_t)((t0)+s_)*CC] = pk_;                               \
    }                                                                             \
  }                                                                               \
} while(0)

__global__ __launch_bounds__(64, 1) void k_scan(
  const u16* __restrict__ rb, const float* __restrict__ wb,
  const u16* __restrict__ kb, const u16* __restrict__ vb,
  const u16* __restrict__ kkb, const u16* __restrict__ bbp,
  const float* __restrict__ wkv_in, u16* __restrict__ yb, float* __restrict__ wkv_out)
{
  const int blk = blockIdx.x;
  const int bh = blk & 127, oct = blk >> 7;
  const int b = bh >> 5, h = bh & 31;
  const int ln = threadIdx.x;
  const int rg = ln >> 4;
  const int cg = ln & 15;
  const int row0 = oct*8 + rg*2;
  const int col0 = cg*4;

  float st[2][4];
  {
    const float* sp0 = &wkv_in[((size_t)bh*64 + row0    )*64 + col0];
    const float* sp1 = &wkv_in[((size_t)bh*64 + row0 + 1)*64 + col0];
    float4 a = *(const float4*)sp0, c = *(const float4*)sp1;
    st[0][0]=a.x; st[0][1]=a.y; st[0][2]=a.z; st[0][3]=a.w;
    st[1][0]=c.x; st[1][1]=c.y; st[1][2]=c.z; st[1][3]=c.w;
  }

  const size_t gc0 = ((size_t)b*TT)*CC + h*64 + col0;
  const size_t gv0 = ((size_t)b*TT)*CC + h*64 + row0;

  SDECL(A) SDECL(B)

  SISSUE(A, 0);
  SISSUE(B, 8);
  SCHUNK(A, 0, 48);
  SISSUE(A, 16);
  SCHUNK(B, 8, 56);
  SISSUE(B, 24);
  for (int c = 1; c < 63; ++c){
    const int t0 = c*16;
    SCHUNK(A, t0, 56);
    SISSUE(A, t0+16);
    SCHUNK(B, t0+8, 56);
    SISSUE(B, t0+24);
  }
  SCHUNK(A, 1008, 56);
  SCHUNK(B, 1016, 0);

  {
    float* wo0 = &wkv_out[((size_t)bh*64 + row0    )*64 + col0];
    float* wo1 = &wkv_out[((size_t)bh*64 + row0 + 1)*64 + col0];
    *(float4*)wo0 = make_float4(st[0][0], st[0][1], st[0][2], st[0][3]);
    *(float4*)wo1 = make_float4(st[1][0], st[1][1], st[1][2], st[1][3]);
  }
}

// ---------- post2 ----------
__global__ __launch_bounds__(256) void k_post2(
  const u16* __restrict__ ybuf, const u16* __restrict__ rbuf,
  const u16* __restrict__ kfb, const u16* __restrict__ vfb,
  const u16* __restrict__ gbuf, const float* __restrict__ rk,
  const float* __restrict__ lnw, const float* __restrict__ lnb, u16* __restrict__ ao)
{
  int grp = blockIdx.x*4 + (threadIdx.x >> 6);
  int n = threadIdx.x & 63;
  int i = grp >> 5, h = grp & 31;
  int c = h*64 + n;
  size_t idx = (size_t)i*CC + c;
  float y = bf2f(ybuf[idx]);
  float s1 = wave_sum64(y);
  float s2 = wave_sum64(y*y);
  float mu = s1 * (1.f/64.f);
  float var = s2 * (1.f/64.f) - mu*mu;
  float yn = (y - mu) * rsqrtf(var + 6.4e-4f) * lnw[c] + lnb[c];
  float rv = bf2f(rbuf[idx]), kv = bf2f(kfb[idx]);
  float s3 = wave_sum64(rv * kv * rk[c]);
  float bonus = s3 * bf2f(vfb[idx]);
  ao[idx] = f2bf((yn + bonus) * bf2f(gbuf[idx]));
}

// ---------- shift_state_out = x[:, -1] (runs LAST; d_out scratch dead by then) ----------
__global__ __launch_bounds__(256) void k_shift(const float* __restrict__ x, float* __restrict__ so){
  int i = blockIdx.x*256 + threadIdx.x;
  int b = i >> 9, c4 = (i & 511)*4;
  *(float4*)&so[(size_t)b*CC + c4] = *(const float4*)&x[((size_t)(b*TT + TT-1))*CC + c4];
}

// ---------- launch ----------
extern "C" void kernel_launch(void* const* d_in, const int* in_sizes, int n_in,
                              void* d_out, int out_size, void* d_ws, size_t ws_size,
                              hipStream_t stream)
{
  const float* x        = (const float*)d_in[0];
  const float* shift_in = (const float*)d_in[1];
  const float* wkv_in   = (const float*)d_in[2];
  const float* v_first  = (const float*)d_in[3];
  const float* x_r = (const float*)d_in[4];
  const float* x_w = (const float*)d_in[5];
  const float* x_k = (const float*)d_in[6];
  const float* x_v = (const float*)d_in[7];
  const float* x_a = (const float*)d_in[8];
  const float* x_g = (const float*)d_in[9];
  const float* w0 = (const float*)d_in[10];
  const float* w1 = (const float*)d_in[11];
  const float* w2 = (const float*)d_in[12];
  const float* a0 = (const float*)d_in[13];
  const float* a1 = (const float*)d_in[14];
  const float* a2 = (const float*)d_in[15];
  const float* v0 = (const float*)d_in[16];
  const float* v1 = (const float*)d_in[17];
  const float* v2 = (const float*)d_in[18];
  const float* g1 = (const float*)d_in[19];
  const float* g2 = (const float*)d_in[20];
  const float* k_k = (const float*)d_in[21];
  const float* k_a = (const float*)d_in[22];
  const float* r_k = (const float*)d_in[23];
  const float* Wr = (const float*)d_in[24];
  const float* Wk = (const float*)d_in[25];
  const float* Wv = (const float*)d_in[26];
  const float* Wo = (const float*)d_in[27];
  const float* ln_w = (const float*)d_in[28];
  const float* ln_b = (const float*)d_in[29];

  // ---- ws layout ----
  char* ws = (char*)d_ws;
  u16* WOB  = (u16*)(ws + 0);
  u16* WRB  = (u16*)(ws + 8388608);
  u16* B2W  = (u16*)(ws + 36175872);
  u16* PBUF = (u16*)(ws + 38797312);
  u16* RB   = (u16*)(ws + 44040192);
  u16* KB   = (u16*)(ws + 60817408);
  u16* VB   = (u16*)(ws + 77594624);
  u16* YB   = (u16*)(ws + 94371840);
  float* DEC  = (float*)(ws + 8388608);
  u16* AO   = (u16*)(ws + 8388608);

  // ---- d_out scratch ----
  float* out       = (float*)d_out;
  float* shift_out = out + 8388608;
  float* wkv_out   = out + 8396800;
  float* vf_out    = out + 8921088;
  u16* XRKV = (u16*)d_out;
  u16* WINb = (u16*)d_out;
  u16* AINb = (u16*)((char*)d_out + 16777216);
  u16* VINb = (u16*)((char*)d_out + 35684352);

  // weight prep
  k_cast4<<<16384, 256, 0, stream>>>(Wr, Wk, Wv, Wo, (u16*)ws);
  k_tpadA<<<2560, 256, 0, stream>>>(w1, a1, v1, g1, w2, a2, v2, g2, (u16*)ws);

  // token-shift mix precompute
  k_prep4<<<8192, 256, 0, stream>>>(x, shift_in, x_r, x_k, x_v, x_w,
                                    XRKV, XRKV + 8388608u, XRKV + 16777216u, XRKV + 25165824u);

  // fused r/k/v + stage-1 GEMM (1D grid, XCD-chunked swizzle)
  k_gemm_rkv<<<1696, 256, 0, stream>>>(XRKV, x, shift_in, x_a, x_g,
                                       WRB, (float*)PBUF, RB, 2048, 2048, 2048, 2048, 53);

  // fused stage-2 GEMMs
  k_gemm_s2<<<2048, 256, 0, stream>>>(PBUF, nullptr, nullptr, nullptr, nullptr,
                                      B2W, nullptr, (u16*)d_out, 0, 640, 128, 2048, 64);

  // elementwise post
  k_post1<<<32768, 256, 0, stream>>>(KB, VB, WINb, AINb, VINb, v_first,
                                     w0, a0, v0, k_k, k_a, DEC);

  // sequential WKV scan (asm-pinned prefetch)
  k_scan<<<1024, 64, 0, stream>>>(RB, DEC, KB, VB, VINb, AINb, wkv_in, YB, wkv_out);

  // groupnorm + bonus + gate
  k_post2<<<32768, 256, 0, stream>>>(YB, RB, KB, VB, (u16*)((char*)d_out + 52461568),
                                     r_k, ln_w, ln_b, AO);

  // final GEMM -> out
  k_gemm_fin<<<512, 256, 0, stream>>>(AO, nullptr, nullptr, nullptr, nullptr,
                                      WOB, out, nullptr, 2048, 2048, 2048, 2048, 16);

  // small outputs last (XV dead; shift_out region safe now)
  k_shift<<<8, 256, 0, stream>>>(x, shift_out);
  hipMemcpyAsync(vf_out, v_first, 33554432, hipMemcpyDeviceToDevice, stream);
}